// Round 2
// baseline (559.326 us; speedup 1.0000x reference)
//
#include <hip/hip_runtime.h>

typedef __bf16 bf16;
typedef __attribute__((ext_vector_type(8))) __bf16 bf16x8;
typedef __attribute__((ext_vector_type(4))) float f32x4;
typedef __attribute__((ext_vector_type(4))) unsigned int u32x4;

#define B_ 4
#define S_ 2048
#define D_ 1024
#define H_ 16
#define HD_ 64

// ---------------- pass 0: weight transpose+convert (K,N)fp32 -> (N,K)bf16 ----
__global__ __launch_bounds__(256) void transpose_cvt(
    const float* __restrict__ W0, const float* __restrict__ W1,
    const float* __restrict__ W2, const float* __restrict__ W3,
    bf16* __restrict__ T0, bf16* __restrict__ T1,
    bf16* __restrict__ T2, bf16* __restrict__ T3)
{
    __shared__ float tile[32][33];
    int z = blockIdx.z;
    const float* W = (z == 0) ? W0 : (z == 1) ? W1 : (z == 2) ? W2 : W3;
    bf16*        T = (z == 0) ? T0 : (z == 1) ? T1 : (z == 2) ? T2 : T3;
    int bx = blockIdx.x * 32, by = blockIdx.y * 32;
    int tx = threadIdx.x & 31, ty = threadIdx.x >> 5;
    #pragma unroll
    for (int j = 0; j < 32; j += 8)
        tile[ty + j][tx] = W[(size_t)(by + ty + j) * D_ + bx + tx];
    __syncthreads();
    #pragma unroll
    for (int j = 0; j < 32; j += 8)
        T[(size_t)(bx + ty + j) * D_ + by + tx] = (bf16)tile[tx][ty + j];
}

// ---------------- pass 1: fused QKV projection GEMM ----------------
// C(8192x1024) = X(fp32) @ W, WT(N,K) bf16 in ws. 128x128 tile, BK=32,
// 4 waves each 64x64 via 4x4 of 16x16x32 MFMA. Epilogue -> (b,h,s,hd) bf16.
__global__ __launch_bounds__(256) void qkv_gemm(
    const float* __restrict__ X,
    const bf16* __restrict__ WqT, const bf16* __restrict__ WkT, const bf16* __restrict__ WvT,
    const float* __restrict__ bq, const float* __restrict__ bk, const float* __restrict__ bv,
    bf16* __restrict__ Qo, bf16* __restrict__ Ko, bf16* __restrict__ Vo)
{
    const int z = blockIdx.z;
    const bf16*  WT   = (z == 0) ? WqT : (z == 1) ? WkT : WvT;
    const float* bias = (z == 0) ? bq  : (z == 1) ? bk  : bv;
    bf16*        out  = (z == 0) ? Qo  : (z == 1) ? Ko  : Vo;
    const float scale = (z == 0) ? 0.125f : 1.0f;  // fold 1/sqrt(HD) into Q

    __shared__ bf16 As[128 * 32];
    __shared__ bf16 Bs[128 * 32];

    const int t = threadIdx.x;
    const int lid = t & 63, w = t >> 6;
    const int wm = w & 1, wn = w >> 1;
    const int lrow = lid & 15, quad = lid >> 4;
    const int m0 = blockIdx.y * 128, n0 = blockIdx.x * 128;

    const float* Ag = X  + (size_t)m0 * D_;
    const bf16*  Bg = WT + (size_t)n0 * D_;

    f32x4 acc[4][4] = {};

    for (int k0 = 0; k0 < D_; k0 += 32) {
        __syncthreads();
        #pragma unroll
        for (int i = 0; i < 2; ++i) {
            int c = t + i * 256;            // 512 chunks of 8 elems per tile
            int row = c >> 2, k8 = (c & 3) << 3;
            const float* xg = Ag + (size_t)row * D_ + k0 + k8;
            f32x4 x0 = *(const f32x4*)(xg);
            f32x4 x1 = *(const f32x4*)(xg + 4);
            bf16x8 xv;
            #pragma unroll
            for (int j = 0; j < 4; ++j) { xv[j] = (bf16)x0[j]; xv[4 + j] = (bf16)x1[j]; }
            *(bf16x8*)(As + row * 32 + k8) = xv;
            *(u32x4*)(Bs + row * 32 + k8) = *(const u32x4*)(Bg + (size_t)row * D_ + k0 + k8);
        }
        __syncthreads();
        bf16x8 a[4], b[4];
        #pragma unroll
        for (int mb = 0; mb < 4; ++mb)
            a[mb] = *(const bf16x8*)(As + (wm * 64 + mb * 16 + lrow) * 32 + quad * 8);
        #pragma unroll
        for (int nb = 0; nb < 4; ++nb)
            b[nb] = *(const bf16x8*)(Bs + (wn * 64 + nb * 16 + lrow) * 32 + quad * 8);
        #pragma unroll
        for (int mb = 0; mb < 4; ++mb)
            #pragma unroll
            for (int nb = 0; nb < 4; ++nb)
                acc[mb][nb] = __builtin_amdgcn_mfma_f32_16x16x32_bf16(a[mb], b[nb], acc[mb][nb], 0, 0, 0);
    }

    #pragma unroll
    for (int mb = 0; mb < 4; ++mb) {
        #pragma unroll
        for (int nb = 0; nb < 4; ++nb) {
            int gn = n0 + wn * 64 + nb * 16 + lrow;
            float bsv = bias[gn];
            int h = gn >> 6, hd = gn & 63;
            #pragma unroll
            for (int r = 0; r < 4; ++r) {
                int gm = m0 + wm * 64 + mb * 16 + quad * 4 + r;
                int bb = gm >> 11, s = gm & 2047;
                float v = (acc[mb][nb][r] + bsv) * scale;
                out[(((size_t)(bb * H_ + h)) * S_ + s) * HD_ + hd] = (bf16)v;
            }
        }
    }
}

// ---------------- pass 2: causal flash attention ----------------
// block = 64 queries of one (b,h); 4 waves x 16 query rows. Bc=64 key tiles.
__global__ __launch_bounds__(256) void attn_fwd(
    const bf16* __restrict__ Q, const bf16* __restrict__ K,
    const bf16* __restrict__ V, bf16* __restrict__ O)
{
    __shared__ bf16 Ks[64 * 72];        // [key][hd], pad stride 72
    __shared__ bf16 Vt[64 * 72];        // [hd][key], transposed
    __shared__ bf16 Ps[4 * 16 * 72];    // per-wave P round-trip

    const int qtile = blockIdx.x, bh = blockIdx.y;
    const int t = threadIdx.x, lid = t & 63, w = t >> 6;
    const int lrow = lid & 15, quad = lid >> 4;
    const int qbase = qtile * 64;

    const bf16* Qp = Q + ((size_t)bh * S_ + qbase + w * 16) * HD_;
    bf16x8 qf[2];
    #pragma unroll
    for (int ks = 0; ks < 2; ++ks)
        qf[ks] = *(const bf16x8*)(Qp + lrow * HD_ + ks * 32 + quad * 8);

    f32x4 o_acc[4] = {};
    float m_i[4], l_i[4];
    #pragma unroll
    for (int r = 0; r < 4; ++r) { m_i[r] = -3.0e4f; l_i[r] = 0.0f; }

    for (int kt = 0; kt <= qtile; ++kt) {
        const bf16* Kp = K + ((size_t)bh * S_ + kt * 64) * HD_;
        const bf16* Vp = V + ((size_t)bh * S_ + kt * 64) * HD_;
        __syncthreads();
        #pragma unroll
        for (int i = 0; i < 2; ++i) {
            int c = t + i * 256;
            int key = c >> 3, hd0 = (c & 7) << 3;
            *(u32x4*)(Ks + key * 72 + hd0) = *(const u32x4*)(Kp + (size_t)key * HD_ + hd0);
            bf16x8 vv = *(const bf16x8*)(Vp + (size_t)key * HD_ + hd0);
            #pragma unroll
            for (int j = 0; j < 8; ++j)
                Vt[(hd0 + j) * 72 + key] = vv[j];
        }
        __syncthreads();

        // S = Q K^T  (Q pre-scaled)
        f32x4 sa[4] = {};
        #pragma unroll
        for (int ks = 0; ks < 2; ++ks) {
            #pragma unroll
            for (int nb = 0; nb < 4; ++nb) {
                bf16x8 kf = *(const bf16x8*)(Ks + (nb * 16 + lrow) * 72 + ks * 32 + quad * 8);
                sa[nb] = __builtin_amdgcn_mfma_f32_16x16x32_bf16(qf[ks], kf, sa[nb], 0, 0, 0);
            }
        }
        if (kt == qtile) {  // diagonal tile: causal mask
            #pragma unroll
            for (int nb = 0; nb < 4; ++nb) {
                int key = nb * 16 + lrow;
                #pragma unroll
                for (int r = 0; r < 4; ++r) {
                    int qr = w * 16 + quad * 4 + r;
                    if (key > qr) sa[nb][r] = -3.0e4f;
                }
            }
        }

        // online softmax (row = (quad, r); 16 lanes of the quad hold the keys)
        float rm[4], rs[4], al[4], p[4][4];
        #pragma unroll
        for (int r = 0; r < 4; ++r)
            rm[r] = fmaxf(fmaxf(sa[0][r], sa[1][r]), fmaxf(sa[2][r], sa[3][r]));
        #pragma unroll
        for (int off = 8; off >= 1; off >>= 1)
            #pragma unroll
            for (int r = 0; r < 4; ++r)
                rm[r] = fmaxf(rm[r], __shfl_xor(rm[r], off, 16));
        #pragma unroll
        for (int r = 0; r < 4; ++r) {
            float mnew = fmaxf(m_i[r], rm[r]);
            al[r] = __expf(m_i[r] - mnew);
            m_i[r] = mnew;
        }
        #pragma unroll
        for (int nb = 0; nb < 4; ++nb)
            #pragma unroll
            for (int r = 0; r < 4; ++r)
                p[nb][r] = __expf(sa[nb][r] - m_i[r]);
        #pragma unroll
        for (int r = 0; r < 4; ++r)
            rs[r] = p[0][r] + p[1][r] + p[2][r] + p[3][r];
        #pragma unroll
        for (int off = 8; off >= 1; off >>= 1)
            #pragma unroll
            for (int r = 0; r < 4; ++r)
                rs[r] += __shfl_xor(rs[r], off, 16);
        #pragma unroll
        for (int r = 0; r < 4; ++r)
            l_i[r] = l_i[r] * al[r] + rs[r];
        #pragma unroll
        for (int nb = 0; nb < 4; ++nb)
            #pragma unroll
            for (int r = 0; r < 4; ++r)
                o_acc[nb][r] *= al[r];

        // P: C-layout -> LDS -> A-layout (wave-private region, in-order LDS)
        bf16* Pw = Ps + w * 16 * 72;
        #pragma unroll
        for (int nb = 0; nb < 4; ++nb)
            #pragma unroll
            for (int r = 0; r < 4; ++r)
                Pw[(quad * 4 + r) * 72 + nb * 16 + lrow] = (bf16)p[nb][r];
        asm volatile("s_waitcnt lgkmcnt(0)" ::: "memory");

        #pragma unroll
        for (int ks = 0; ks < 2; ++ks) {
            bf16x8 pf = *(const bf16x8*)(Pw + lrow * 72 + ks * 32 + quad * 8);
            #pragma unroll
            for (int nb = 0; nb < 4; ++nb) {
                bf16x8 vf = *(const bf16x8*)(Vt + (nb * 16 + lrow) * 72 + ks * 32 + quad * 8);
                o_acc[nb] = __builtin_amdgcn_mfma_f32_16x16x32_bf16(pf, vf, o_acc[nb], 0, 0, 0);
            }
        }
    }

    const int b = bh >> 4, h = bh & 15;
    #pragma unroll
    for (int nb = 0; nb < 4; ++nb) {
        #pragma unroll
        for (int r = 0; r < 4; ++r) {
            int s = qbase + w * 16 + quad * 4 + r;
            int hd = nb * 16 + lrow;
            float v = o_acc[nb][r] / l_i[r];
            O[((size_t)b * S_ + s) * D_ + h * 64 + hd] = (bf16)v;
        }
    }
}

// ---------------- pass 3: output projection GEMM (fp32 out) ----------------
__global__ __launch_bounds__(256) void proj_gemm(
    const bf16* __restrict__ A, const bf16* __restrict__ WpT,
    const float* __restrict__ bp, float* __restrict__ out)
{
    __shared__ bf16 As[128 * 32];
    __shared__ bf16 Bs[128 * 32];

    const int t = threadIdx.x;
    const int lid = t & 63, w = t >> 6;
    const int wm = w & 1, wn = w >> 1;
    const int lrow = lid & 15, quad = lid >> 4;
    const int m0 = blockIdx.y * 128, n0 = blockIdx.x * 128;

    const bf16* Ag = A   + (size_t)m0 * D_;
    const bf16* Bg = WpT + (size_t)n0 * D_;

    f32x4 acc[4][4] = {};

    for (int k0 = 0; k0 < D_; k0 += 32) {
        __syncthreads();
        #pragma unroll
        for (int i = 0; i < 2; ++i) {
            int c = t + i * 256;
            int row = c >> 2, k8 = (c & 3) << 3;
            *(u32x4*)(As + row * 32 + k8) = *(const u32x4*)(Ag + (size_t)row * D_ + k0 + k8);
            *(u32x4*)(Bs + row * 32 + k8) = *(const u32x4*)(Bg + (size_t)row * D_ + k0 + k8);
        }
        __syncthreads();
        bf16x8 a[4], b[4];
        #pragma unroll
        for (int mb = 0; mb < 4; ++mb)
            a[mb] = *(const bf16x8*)(As + (wm * 64 + mb * 16 + lrow) * 32 + quad * 8);
        #pragma unroll
        for (int nb = 0; nb < 4; ++nb)
            b[nb] = *(const bf16x8*)(Bs + (wn * 64 + nb * 16 + lrow) * 32 + quad * 8);
        #pragma unroll
        for (int mb = 0; mb < 4; ++mb)
            #pragma unroll
            for (int nb = 0; nb < 4; ++nb)
                acc[mb][nb] = __builtin_amdgcn_mfma_f32_16x16x32_bf16(a[mb], b[nb], acc[mb][nb], 0, 0, 0);
    }

    #pragma unroll
    for (int mb = 0; mb < 4; ++mb) {
        #pragma unroll
        for (int nb = 0; nb < 4; ++nb) {
            int gn = n0 + wn * 64 + nb * 16 + lrow;
            float bsv = bp[gn];
            #pragma unroll
            for (int r = 0; r < 4; ++r) {
                int gm = m0 + wm * 64 + mb * 16 + quad * 4 + r;
                out[(size_t)gm * D_ + gn] = acc[mb][nb][r] + bsv;
            }
        }
    }
}

// ---------------- launch ----------------
extern "C" void kernel_launch(void* const* d_in, const int* in_sizes, int n_in,
                              void* d_out, int out_size, void* d_ws, size_t ws_size,
                              hipStream_t stream)
{
    const float* x  = (const float*)d_in[0];
    const float* Wq = (const float*)d_in[1];
    const float* bq = (const float*)d_in[2];
    const float* Wk = (const float*)d_in[3];
    const float* bk = (const float*)d_in[4];
    const float* Wv = (const float*)d_in[5];
    const float* bv = (const float*)d_in[6];
    const float* Wp = (const float*)d_in[7];
    const float* bp = (const float*)d_in[8];

    bf16* ws = (bf16*)d_ws;
    const size_t WSZ = (size_t)D_ * D_;        // 1,048,576 elems
    const size_t BIG = (size_t)B_ * S_ * D_;   // 8,388,608 elems
    bf16* WqT = ws;
    bf16* WkT = WqT + WSZ;
    bf16* WvT = WkT + WSZ;
    bf16* WpT = WvT + WSZ;
    bf16* Qb  = WpT + WSZ;
    bf16* Kb  = Qb + BIG;
    bf16* Vb  = Kb + BIG;
    bf16* Ab  = Vb + BIG;   // total ~75.5 MB bf16

    transpose_cvt<<<dim3(32, 32, 4), 256, 0, stream>>>(
        Wq, Wk, Wv, Wp, WqT, WkT, WvT, WpT);

    qkv_gemm<<<dim3(8, 64, 3), 256, 0, stream>>>(
        x, WqT, WkT, WvT, bq, bk, bv, Qb, Kb, Vb);

    attn_fwd<<<dim3(32, 64), 256, 0, stream>>>(Qb, Kb, Vb, Ab);

    proj_gemm<<<dim3(8, 64), 256, 0, stream>>>(Ab, WpT, bp, (float*)d_out);
}

// Round 3
// 466.023 us; speedup vs baseline: 1.2002x; 1.2002x over previous
//
#include <hip/hip_runtime.h>

typedef __bf16 bf16;
typedef __attribute__((ext_vector_type(8))) __bf16 bf16x8;
typedef __attribute__((ext_vector_type(4))) float f32x4;
typedef __attribute__((ext_vector_type(4))) unsigned int u32x4;

#define B_ 4
#define S_ 2048
#define D_ 1024
#define H_ 16
#define HD_ 64

// ---------------- pass 0: weight transpose+convert (K,N)fp32 -> (N,K)bf16 ----
__global__ __launch_bounds__(256) void transpose_cvt(
    const float* __restrict__ W0, const float* __restrict__ W1,
    const float* __restrict__ W2, const float* __restrict__ W3,
    bf16* __restrict__ T0, bf16* __restrict__ T1,
    bf16* __restrict__ T2, bf16* __restrict__ T3)
{
    __shared__ float tile[32][33];
    int z = blockIdx.z;
    const float* W = (z == 0) ? W0 : (z == 1) ? W1 : (z == 2) ? W2 : W3;
    bf16*        T = (z == 0) ? T0 : (z == 1) ? T1 : (z == 2) ? T2 : T3;
    int bx = blockIdx.x * 32, by = blockIdx.y * 32;
    int tx = threadIdx.x & 31, ty = threadIdx.x >> 5;
    #pragma unroll
    for (int j = 0; j < 32; j += 8)
        tile[ty + j][tx] = W[(size_t)(by + ty + j) * D_ + bx + tx];
    __syncthreads();
    #pragma unroll
    for (int j = 0; j < 32; j += 8)
        T[(size_t)(bx + ty + j) * D_ + by + tx] = (bf16)tile[tx][ty + j];
}

// ---------------- pass 1: fused QKV projection GEMM ----------------
// C(8192x1024) = X(fp32) @ W, WT(N,K) bf16 in ws. 128x128 tile, BK=32.
// Epilogue: Q,K -> (b,h,s,hd) bf16 (Q pre-scaled 1/8); V -> (b,h,hd,s) bf16.
__global__ __launch_bounds__(256) void qkv_gemm(
    const float* __restrict__ X,
    const bf16* __restrict__ WqT, const bf16* __restrict__ WkT, const bf16* __restrict__ WvT,
    const float* __restrict__ bq, const float* __restrict__ bk, const float* __restrict__ bv,
    bf16* __restrict__ Qo, bf16* __restrict__ Ko, bf16* __restrict__ Vo)
{
    const int z = blockIdx.z;
    const bf16*  WT   = (z == 0) ? WqT : (z == 1) ? WkT : WvT;
    const float* bias = (z == 0) ? bq  : (z == 1) ? bk  : bv;
    bf16*        out  = (z == 0) ? Qo  : (z == 1) ? Ko  : Vo;
    const float scale = (z == 0) ? 0.125f : 1.0f;  // fold 1/sqrt(HD) into Q

    __shared__ bf16 As[128 * 32];
    __shared__ bf16 Bs[128 * 32];

    const int t = threadIdx.x;
    const int lid = t & 63, w = t >> 6;
    const int wm = w & 1, wn = w >> 1;
    const int lrow = lid & 15, quad = lid >> 4;
    const int m0 = blockIdx.y * 128, n0 = blockIdx.x * 128;

    const float* Ag = X  + (size_t)m0 * D_;
    const bf16*  Bg = WT + (size_t)n0 * D_;

    f32x4 acc[4][4] = {};

    for (int k0 = 0; k0 < D_; k0 += 32) {
        __syncthreads();
        #pragma unroll
        for (int i = 0; i < 2; ++i) {
            int c = t + i * 256;            // 512 chunks of 8 elems per tile
            int row = c >> 2, k8 = (c & 3) << 3;
            const float* xg = Ag + (size_t)row * D_ + k0 + k8;
            f32x4 x0 = *(const f32x4*)(xg);
            f32x4 x1 = *(const f32x4*)(xg + 4);
            bf16x8 xv;
            #pragma unroll
            for (int j = 0; j < 4; ++j) { xv[j] = (bf16)x0[j]; xv[4 + j] = (bf16)x1[j]; }
            *(bf16x8*)(As + row * 32 + k8) = xv;
            *(u32x4*)(Bs + row * 32 + k8) = *(const u32x4*)(Bg + (size_t)row * D_ + k0 + k8);
        }
        __syncthreads();
        bf16x8 a[4], b[4];
        #pragma unroll
        for (int mb = 0; mb < 4; ++mb)
            a[mb] = *(const bf16x8*)(As + (wm * 64 + mb * 16 + lrow) * 32 + quad * 8);
        #pragma unroll
        for (int nb = 0; nb < 4; ++nb)
            b[nb] = *(const bf16x8*)(Bs + (wn * 64 + nb * 16 + lrow) * 32 + quad * 8);
        #pragma unroll
        for (int mb = 0; mb < 4; ++mb)
            #pragma unroll
            for (int nb = 0; nb < 4; ++nb)
                acc[mb][nb] = __builtin_amdgcn_mfma_f32_16x16x32_bf16(a[mb], b[nb], acc[mb][nb], 0, 0, 0);
    }

    #pragma unroll
    for (int mb = 0; mb < 4; ++mb) {
        #pragma unroll
        for (int nb = 0; nb < 4; ++nb) {
            int gn = n0 + wn * 64 + nb * 16 + lrow;
            float bsv = bias[gn];
            int h = gn >> 6, hd = gn & 63;
            #pragma unroll
            for (int r = 0; r < 4; ++r) {
                int gm = m0 + wm * 64 + mb * 16 + quad * 4 + r;
                int bb = gm >> 11, s = gm & 2047;
                float v = (acc[mb][nb][r] + bsv) * scale;
                if (z == 2) {
                    // V^T: [b, h, hd, s]
                    out[(((size_t)(bb * H_ + h)) * HD_ + hd) * S_ + s] = (bf16)v;
                } else {
                    // Q/K: [b, h, s, hd]
                    out[(((size_t)(bb * H_ + h)) * S_ + s) * HD_ + hd] = (bf16)v;
                }
            }
        }
    }
}

// ---------------- pass 2: causal flash attention ----------------
// block = 128 queries of one (b,h); 4 waves x 32 query rows (2 m-tiles).
// K-tiles of 64 keys. V comes pre-transposed [b,h,hd,s].
__global__ __launch_bounds__(256) void attn_fwd(
    const bf16* __restrict__ Q, const bf16* __restrict__ K,
    const bf16* __restrict__ Vt, bf16* __restrict__ O)
{
    __shared__ bf16 Ks[64 * 72];        // [key][hd], stride 72 (144B, 16B-aligned)
    __shared__ bf16 Vs[64 * 72];        // [hd][key], staged directly from V^T
    __shared__ bf16 Ps[4 * 32 * 72];    // per-wave P round-trip, stride 72

    const int qtile = (gridDim.x - 1) - blockIdx.x;   // big blocks dispatch first
    const int bh = blockIdx.y;
    const int t = threadIdx.x, lid = t & 63, w = t >> 6;
    const int lrow = lid & 15, quad = lid >> 4;
    const int qbase = qtile * 128;

    // Q fragments: 2 m-tiles x 2 k-frags
    const bf16* Qp = Q + ((size_t)bh * S_ + qbase + w * 32) * HD_;
    bf16x8 qf[2][2];
    #pragma unroll
    for (int mt = 0; mt < 2; ++mt)
        #pragma unroll
        for (int ks = 0; ks < 2; ++ks)
            qf[mt][ks] = *(const bf16x8*)(Qp + (mt * 16 + lrow) * HD_ + ks * 32 + quad * 8);

    f32x4 o_acc[2][4] = {};
    float m_i[2][4], l_i[2][4];
    #pragma unroll
    for (int mt = 0; mt < 2; ++mt)
        #pragma unroll
        for (int r = 0; r < 4; ++r) { m_i[mt][r] = -3.0e4f; l_i[mt][r] = 0.0f; }

    const int ktmax = 2 * qtile + 1;
    for (int kt = 0; kt <= ktmax; ++kt) {
        const bf16* Kp = K  + ((size_t)bh * S_ + kt * 64) * HD_;
        const bf16* Vp = Vt + ((size_t)bh * HD_) * S_ + kt * 64;
        __syncthreads();
        #pragma unroll
        for (int i = 0; i < 2; ++i) {
            int c = t + i * 256;
            int row = c >> 3, c8 = (c & 7) << 3;   // row: key for K, hd for V
            *(u32x4*)(Ks + row * 72 + c8) = *(const u32x4*)(Kp + (size_t)row * HD_ + c8);
            *(u32x4*)(Vs + row * 72 + c8) = *(const u32x4*)(Vp + (size_t)row * S_ + c8);
        }
        __syncthreads();

        // S = Q K^T  (Q pre-scaled)
        f32x4 sa[2][4] = {};
        #pragma unroll
        for (int ks = 0; ks < 2; ++ks) {
            #pragma unroll
            for (int nb = 0; nb < 4; ++nb) {
                bf16x8 kf = *(const bf16x8*)(Ks + (nb * 16 + lrow) * 72 + ks * 32 + quad * 8);
                #pragma unroll
                for (int mt = 0; mt < 2; ++mt)
                    sa[mt][nb] = __builtin_amdgcn_mfma_f32_16x16x32_bf16(qf[mt][ks], kf, sa[mt][nb], 0, 0, 0);
            }
        }
        if (kt >= 2 * qtile) {  // possibly-diagonal tiles: causal mask
            #pragma unroll
            for (int mt = 0; mt < 2; ++mt)
                #pragma unroll
                for (int nb = 0; nb < 4; ++nb) {
                    int key = kt * 64 + nb * 16 + lrow;
                    #pragma unroll
                    for (int r = 0; r < 4; ++r) {
                        int qr = qbase + w * 32 + mt * 16 + quad * 4 + r;
                        if (key > qr) sa[mt][nb][r] = -3.0e4f;
                    }
                }
        }

        // online softmax per m-tile (row = (quad, r); 16 lanes hold the keys)
        float p[2][4][4];
        #pragma unroll
        for (int mt = 0; mt < 2; ++mt) {
            float rm[4], rs[4], al[4];
            #pragma unroll
            for (int r = 0; r < 4; ++r)
                rm[r] = fmaxf(fmaxf(sa[mt][0][r], sa[mt][1][r]), fmaxf(sa[mt][2][r], sa[mt][3][r]));
            #pragma unroll
            for (int off = 8; off >= 1; off >>= 1)
                #pragma unroll
                for (int r = 0; r < 4; ++r)
                    rm[r] = fmaxf(rm[r], __shfl_xor(rm[r], off, 16));
            #pragma unroll
            for (int r = 0; r < 4; ++r) {
                float mnew = fmaxf(m_i[mt][r], rm[r]);
                al[r] = __expf(m_i[mt][r] - mnew);
                m_i[mt][r] = mnew;
            }
            #pragma unroll
            for (int nb = 0; nb < 4; ++nb)
                #pragma unroll
                for (int r = 0; r < 4; ++r)
                    p[mt][nb][r] = __expf(sa[mt][nb][r] - m_i[mt][r]);
            #pragma unroll
            for (int r = 0; r < 4; ++r)
                rs[r] = p[mt][0][r] + p[mt][1][r] + p[mt][2][r] + p[mt][3][r];
            #pragma unroll
            for (int off = 8; off >= 1; off >>= 1)
                #pragma unroll
                for (int r = 0; r < 4; ++r)
                    rs[r] += __shfl_xor(rs[r], off, 16);
            #pragma unroll
            for (int r = 0; r < 4; ++r)
                l_i[mt][r] = l_i[mt][r] * al[r] + rs[r];
            #pragma unroll
            for (int nb = 0; nb < 4; ++nb)
                #pragma unroll
                for (int r = 0; r < 4; ++r)
                    o_acc[mt][nb][r] *= al[r];
        }

        // P: C-layout -> LDS -> A-layout (wave-private region, in-order DS queue)
        bf16* Pw = Ps + w * 32 * 72;
        #pragma unroll
        for (int mt = 0; mt < 2; ++mt)
            #pragma unroll
            for (int nb = 0; nb < 4; ++nb)
                #pragma unroll
                for (int r = 0; r < 4; ++r)
                    Pw[(mt * 16 + quad * 4 + r) * 72 + nb * 16 + lrow] = (bf16)p[mt][nb][r];
        asm volatile("s_waitcnt lgkmcnt(0)" ::: "memory");

        #pragma unroll
        for (int ks = 0; ks < 2; ++ks) {
            bf16x8 pf[2];
            #pragma unroll
            for (int mt = 0; mt < 2; ++mt)
                pf[mt] = *(const bf16x8*)(Pw + (mt * 16 + lrow) * 72 + ks * 32 + quad * 8);
            #pragma unroll
            for (int nb = 0; nb < 4; ++nb) {
                bf16x8 vf = *(const bf16x8*)(Vs + (nb * 16 + lrow) * 72 + ks * 32 + quad * 8);
                #pragma unroll
                for (int mt = 0; mt < 2; ++mt)
                    o_acc[mt][nb] = __builtin_amdgcn_mfma_f32_16x16x32_bf16(pf[mt], vf, o_acc[mt][nb], 0, 0, 0);
            }
        }
    }

    const int b = bh >> 4, h = bh & 15;
    #pragma unroll
    for (int mt = 0; mt < 2; ++mt)
        #pragma unroll
        for (int nb = 0; nb < 4; ++nb)
            #pragma unroll
            for (int r = 0; r < 4; ++r) {
                int s = qbase + w * 32 + mt * 16 + quad * 4 + r;
                int hd = nb * 16 + lrow;
                float v = o_acc[mt][nb][r] / l_i[mt][r];
                O[((size_t)b * S_ + s) * D_ + h * 64 + hd] = (bf16)v;
            }
}

// ---------------- pass 3: output projection GEMM (fp32 out) ----------------
__global__ __launch_bounds__(256) void proj_gemm(
    const bf16* __restrict__ A, const bf16* __restrict__ WpT,
    const float* __restrict__ bp, float* __restrict__ out)
{
    __shared__ bf16 As[128 * 32];
    __shared__ bf16 Bs[128 * 32];

    const int t = threadIdx.x;
    const int lid = t & 63, w = t >> 6;
    const int wm = w & 1, wn = w >> 1;
    const int lrow = lid & 15, quad = lid >> 4;
    const int m0 = blockIdx.y * 128, n0 = blockIdx.x * 128;

    const bf16* Ag = A   + (size_t)m0 * D_;
    const bf16* Bg = WpT + (size_t)n0 * D_;

    f32x4 acc[4][4] = {};

    for (int k0 = 0; k0 < D_; k0 += 32) {
        __syncthreads();
        #pragma unroll
        for (int i = 0; i < 2; ++i) {
            int c = t + i * 256;
            int row = c >> 2, k8 = (c & 3) << 3;
            *(u32x4*)(As + row * 32 + k8) = *(const u32x4*)(Ag + (size_t)row * D_ + k0 + k8);
            *(u32x4*)(Bs + row * 32 + k8) = *(const u32x4*)(Bg + (size_t)row * D_ + k0 + k8);
        }
        __syncthreads();
        bf16x8 a[4], b[4];
        #pragma unroll
        for (int mb = 0; mb < 4; ++mb)
            a[mb] = *(const bf16x8*)(As + (wm * 64 + mb * 16 + lrow) * 32 + quad * 8);
        #pragma unroll
        for (int nb = 0; nb < 4; ++nb)
            b[nb] = *(const bf16x8*)(Bs + (wn * 64 + nb * 16 + lrow) * 32 + quad * 8);
        #pragma unroll
        for (int mb = 0; mb < 4; ++mb)
            #pragma unroll
            for (int nb = 0; nb < 4; ++nb)
                acc[mb][nb] = __builtin_amdgcn_mfma_f32_16x16x32_bf16(a[mb], b[nb], acc[mb][nb], 0, 0, 0);
    }

    #pragma unroll
    for (int mb = 0; mb < 4; ++mb) {
        #pragma unroll
        for (int nb = 0; nb < 4; ++nb) {
            int gn = n0 + wn * 64 + nb * 16 + lrow;
            float bsv = bp[gn];
            #pragma unroll
            for (int r = 0; r < 4; ++r) {
                int gm = m0 + wm * 64 + mb * 16 + quad * 4 + r;
                out[(size_t)gm * D_ + gn] = acc[mb][nb][r] + bsv;
            }
        }
    }
}

// ---------------- launch ----------------
extern "C" void kernel_launch(void* const* d_in, const int* in_sizes, int n_in,
                              void* d_out, int out_size, void* d_ws, size_t ws_size,
                              hipStream_t stream)
{
    const float* x  = (const float*)d_in[0];
    const float* Wq = (const float*)d_in[1];
    const float* bq = (const float*)d_in[2];
    const float* Wk = (const float*)d_in[3];
    const float* bk = (const float*)d_in[4];
    const float* Wv = (const float*)d_in[5];
    const float* bv = (const float*)d_in[6];
    const float* Wp = (const float*)d_in[7];
    const float* bp = (const float*)d_in[8];

    bf16* ws = (bf16*)d_ws;
    const size_t WSZ = (size_t)D_ * D_;        // 1,048,576 elems
    const size_t BIG = (size_t)B_ * S_ * D_;   // 8,388,608 elems
    bf16* WqT = ws;
    bf16* WkT = WqT + WSZ;
    bf16* WvT = WkT + WSZ;
    bf16* WpT = WvT + WSZ;
    bf16* Qb  = WpT + WSZ;
    bf16* Kb  = Qb + BIG;
    bf16* Vb  = Kb + BIG;    // V^T layout [b,h,hd,s]
    bf16* Ab  = Vb + BIG;    // total ~75.5 MB bf16

    transpose_cvt<<<dim3(32, 32, 4), 256, 0, stream>>>(
        Wq, Wk, Wv, Wp, WqT, WkT, WvT, WpT);

    qkv_gemm<<<dim3(8, 64, 3), 256, 0, stream>>>(
        x, WqT, WkT, WvT, bq, bk, bv, Qb, Kb, Vb);

    attn_fwd<<<dim3(16, 64), 256, 0, stream>>>(Qb, Kb, Vb, Ab);

    proj_gemm<<<dim3(8, 64), 256, 0, stream>>>(Ab, WpT, bp, (float*)d_out);
}

// Round 4
// 401.008 us; speedup vs baseline: 1.3948x; 1.1621x over previous
//
#include <hip/hip_runtime.h>

typedef __bf16 bf16;
typedef __attribute__((ext_vector_type(8))) __bf16 bf16x8;
typedef __attribute__((ext_vector_type(4))) float f32x4;
typedef __attribute__((ext_vector_type(4))) unsigned int u32x4;

#define B_ 4
#define S_ 2048
#define D_ 1024
#define H_ 16
#define HD_ 64

// ---------------- pass 0: weight transpose+convert (K,N)fp32 -> (N,K)bf16 ----
__global__ __launch_bounds__(256) void transpose_cvt(
    const float* __restrict__ W0, const float* __restrict__ W1,
    const float* __restrict__ W2, const float* __restrict__ W3,
    bf16* __restrict__ T0, bf16* __restrict__ T1,
    bf16* __restrict__ T2, bf16* __restrict__ T3)
{
    __shared__ float tile[32][33];
    int z = blockIdx.z;
    const float* W = (z == 0) ? W0 : (z == 1) ? W1 : (z == 2) ? W2 : W3;
    bf16*        T = (z == 0) ? T0 : (z == 1) ? T1 : (z == 2) ? T2 : T3;
    int bx = blockIdx.x * 32, by = blockIdx.y * 32;
    int tx = threadIdx.x & 31, ty = threadIdx.x >> 5;
    #pragma unroll
    for (int j = 0; j < 32; j += 8)
        tile[ty + j][tx] = W[(size_t)(by + ty + j) * D_ + bx + tx];
    __syncthreads();
    #pragma unroll
    for (int j = 0; j < 32; j += 8)
        T[(size_t)(bx + ty + j) * D_ + by + tx] = (bf16)tile[tx][ty + j];
}

// ---------------- pass 1: fused QKV projection GEMM ----------------
// C(8192x1024) = X(fp32) @ W, WT(N,K) bf16 in ws. 128x128 tile, BK=32.
// Epilogue: Q -> (b,h,s,hd) bf16 pre-scaled by log2(e)/sqrt(HD) (exp2-domain
// softmax); K -> (b,h,s,hd); V -> (b,h,hd,s) transposed.
__global__ __launch_bounds__(256) void qkv_gemm(
    const float* __restrict__ X,
    const bf16* __restrict__ WqT, const bf16* __restrict__ WkT, const bf16* __restrict__ WvT,
    const float* __restrict__ bq, const float* __restrict__ bk, const float* __restrict__ bv,
    bf16* __restrict__ Qo, bf16* __restrict__ Ko, bf16* __restrict__ Vo)
{
    const int z = blockIdx.z;
    const bf16*  WT   = (z == 0) ? WqT : (z == 1) ? WkT : WvT;
    const float* bias = (z == 0) ? bq  : (z == 1) ? bk  : bv;
    bf16*        out  = (z == 0) ? Qo  : (z == 1) ? Ko  : Vo;
    // Q scale: 1/sqrt(64) * log2(e) so attention scores are in exp2 domain
    const float scale = (z == 0) ? 0.18033688011112042f : 1.0f;

    __shared__ bf16 As[128 * 32];
    __shared__ bf16 Bs[128 * 32];

    const int t = threadIdx.x;
    const int lid = t & 63, w = t >> 6;
    const int wm = w & 1, wn = w >> 1;
    const int lrow = lid & 15, quad = lid >> 4;
    const int m0 = blockIdx.y * 128, n0 = blockIdx.x * 128;

    const float* Ag = X  + (size_t)m0 * D_;
    const bf16*  Bg = WT + (size_t)n0 * D_;

    f32x4 acc[4][4] = {};

    for (int k0 = 0; k0 < D_; k0 += 32) {
        __syncthreads();
        #pragma unroll
        for (int i = 0; i < 2; ++i) {
            int c = t + i * 256;            // 512 chunks of 8 elems per tile
            int row = c >> 2, k8 = (c & 3) << 3;
            const float* xg = Ag + (size_t)row * D_ + k0 + k8;
            f32x4 x0 = *(const f32x4*)(xg);
            f32x4 x1 = *(const f32x4*)(xg + 4);
            bf16x8 xv;
            #pragma unroll
            for (int j = 0; j < 4; ++j) { xv[j] = (bf16)x0[j]; xv[4 + j] = (bf16)x1[j]; }
            *(bf16x8*)(As + row * 32 + k8) = xv;
            *(u32x4*)(Bs + row * 32 + k8) = *(const u32x4*)(Bg + (size_t)row * D_ + k0 + k8);
        }
        __syncthreads();
        bf16x8 a[4], b[4];
        #pragma unroll
        for (int mb = 0; mb < 4; ++mb)
            a[mb] = *(const bf16x8*)(As + (wm * 64 + mb * 16 + lrow) * 32 + quad * 8);
        #pragma unroll
        for (int nb = 0; nb < 4; ++nb)
            b[nb] = *(const bf16x8*)(Bs + (wn * 64 + nb * 16 + lrow) * 32 + quad * 8);
        #pragma unroll
        for (int mb = 0; mb < 4; ++mb)
            #pragma unroll
            for (int nb = 0; nb < 4; ++nb)
                acc[mb][nb] = __builtin_amdgcn_mfma_f32_16x16x32_bf16(a[mb], b[nb], acc[mb][nb], 0, 0, 0);
    }

    #pragma unroll
    for (int mb = 0; mb < 4; ++mb) {
        #pragma unroll
        for (int nb = 0; nb < 4; ++nb) {
            int gn = n0 + wn * 64 + nb * 16 + lrow;
            float bsv = bias[gn];
            int h = gn >> 6, hd = gn & 63;
            #pragma unroll
            for (int r = 0; r < 4; ++r) {
                int gm = m0 + wm * 64 + mb * 16 + quad * 4 + r;
                int bb = gm >> 11, s = gm & 2047;
                float v = (acc[mb][nb][r] + bsv) * scale;
                if (z == 2) {
                    // V^T: [b, h, hd, s]
                    out[(((size_t)(bb * H_ + h)) * HD_ + hd) * S_ + s] = (bf16)v;
                } else {
                    // Q/K: [b, h, s, hd]
                    out[(((size_t)(bb * H_ + h)) * S_ + s) * HD_ + hd] = (bf16)v;
                }
            }
        }
    }
}

// ---------------- pass 2: causal flash attention ----------------
// Each block processes TWO 128-query tiles: (15 - blockIdx.x) and blockIdx.x,
// giving constant work per block (34 key-tile units) regardless of the
// (undefined) block->CU mapping. 4 waves x 32 query rows per tile.
// V comes pre-transposed [b,h,hd,s]. Softmax in exp2 domain (Q pre-scaled).
__global__ __launch_bounds__(256) void attn_fwd(
    const bf16* __restrict__ Q, const bf16* __restrict__ K,
    const bf16* __restrict__ Vt, bf16* __restrict__ O)
{
    __shared__ bf16 Ks[64 * 72];        // [key][hd], stride 72
    __shared__ bf16 Vs[64 * 72];        // [hd][key], staged from V^T
    __shared__ bf16 Ps[4 * 32 * 72];    // per-wave P round-trip

    const int bh = blockIdx.y;
    const int t = threadIdx.x, lid = t & 63, w = t >> 6;
    const int lrow = lid & 15, quad = lid >> 4;
    const int b = bh >> 4, h = bh & 15;

    #pragma unroll 1
    for (int half = 0; half < 2; ++half) {
        const int qtile = half ? blockIdx.x : (15 - blockIdx.x);
        const int qbase = qtile * 128;

        // Q fragments: 2 m-tiles x 2 k-frags
        const bf16* Qp = Q + ((size_t)bh * S_ + qbase + w * 32) * HD_;
        bf16x8 qf[2][2];
        #pragma unroll
        for (int mt = 0; mt < 2; ++mt)
            #pragma unroll
            for (int ks = 0; ks < 2; ++ks)
                qf[mt][ks] = *(const bf16x8*)(Qp + (mt * 16 + lrow) * HD_ + ks * 32 + quad * 8);

        f32x4 o_acc[2][4] = {};
        float m_i[2][4], l_i[2][4];
        #pragma unroll
        for (int mt = 0; mt < 2; ++mt)
            #pragma unroll
            for (int r = 0; r < 4; ++r) { m_i[mt][r] = -3.0e4f; l_i[mt][r] = 0.0f; }

        const int ktmax = 2 * qtile + 1;
        for (int kt = 0; kt <= ktmax; ++kt) {
            const bf16* Kp = K  + ((size_t)bh * S_ + kt * 64) * HD_;
            const bf16* Vp = Vt + ((size_t)bh * HD_) * S_ + kt * 64;
            __syncthreads();
            #pragma unroll
            for (int i = 0; i < 2; ++i) {
                int c = t + i * 256;
                int row = c >> 3, c8 = (c & 7) << 3;   // row: key for K, hd for V
                *(u32x4*)(Ks + row * 72 + c8) = *(const u32x4*)(Kp + (size_t)row * HD_ + c8);
                *(u32x4*)(Vs + row * 72 + c8) = *(const u32x4*)(Vp + (size_t)row * S_ + c8);
            }
            __syncthreads();

            // S = Q K^T  (Q pre-scaled into exp2 domain)
            f32x4 sa[2][4] = {};
            #pragma unroll
            for (int ks = 0; ks < 2; ++ks) {
                #pragma unroll
                for (int nb = 0; nb < 4; ++nb) {
                    bf16x8 kf = *(const bf16x8*)(Ks + (nb * 16 + lrow) * 72 + ks * 32 + quad * 8);
                    #pragma unroll
                    for (int mt = 0; mt < 2; ++mt)
                        sa[mt][nb] = __builtin_amdgcn_mfma_f32_16x16x32_bf16(qf[mt][ks], kf, sa[mt][nb], 0, 0, 0);
                }
            }
            if (kt >= 2 * qtile) {  // possibly-diagonal tiles: causal mask
                #pragma unroll
                for (int mt = 0; mt < 2; ++mt)
                    #pragma unroll
                    for (int nb = 0; nb < 4; ++nb) {
                        int key = kt * 64 + nb * 16 + lrow;
                        #pragma unroll
                        for (int r = 0; r < 4; ++r) {
                            int qr = qbase + w * 32 + mt * 16 + quad * 4 + r;
                            if (key > qr) sa[mt][nb][r] = -3.0e4f;
                        }
                    }
            }

            // online softmax (exp2 domain), row = (quad, r)
            float p[2][4][4];
            #pragma unroll
            for (int mt = 0; mt < 2; ++mt) {
                float rm[4], rs[4], al[4];
                #pragma unroll
                for (int r = 0; r < 4; ++r)
                    rm[r] = fmaxf(fmaxf(sa[mt][0][r], sa[mt][1][r]), fmaxf(sa[mt][2][r], sa[mt][3][r]));
                #pragma unroll
                for (int off = 8; off >= 1; off >>= 1)
                    #pragma unroll
                    for (int r = 0; r < 4; ++r)
                        rm[r] = fmaxf(rm[r], __shfl_xor(rm[r], off, 16));
                #pragma unroll
                for (int r = 0; r < 4; ++r) {
                    float mnew = fmaxf(m_i[mt][r], rm[r]);
                    al[r] = exp2f(m_i[mt][r] - mnew);
                    m_i[mt][r] = mnew;
                }
                #pragma unroll
                for (int nb = 0; nb < 4; ++nb)
                    #pragma unroll
                    for (int r = 0; r < 4; ++r)
                        p[mt][nb][r] = exp2f(sa[mt][nb][r] - m_i[mt][r]);
                #pragma unroll
                for (int r = 0; r < 4; ++r)
                    rs[r] = p[mt][0][r] + p[mt][1][r] + p[mt][2][r] + p[mt][3][r];
                #pragma unroll
                for (int off = 8; off >= 1; off >>= 1)
                    #pragma unroll
                    for (int r = 0; r < 4; ++r)
                        rs[r] += __shfl_xor(rs[r], off, 16);
                #pragma unroll
                for (int r = 0; r < 4; ++r)
                    l_i[mt][r] = l_i[mt][r] * al[r] + rs[r];
                #pragma unroll
                for (int nb = 0; nb < 4; ++nb)
                    #pragma unroll
                    for (int r = 0; r < 4; ++r)
                        o_acc[mt][nb][r] *= al[r];
            }

            // P: C-layout -> LDS -> A-layout (wave-private region)
            bf16* Pw = Ps + w * 32 * 72;
            #pragma unroll
            for (int mt = 0; mt < 2; ++mt)
                #pragma unroll
                for (int nb = 0; nb < 4; ++nb)
                    #pragma unroll
                    for (int r = 0; r < 4; ++r)
                        Pw[(mt * 16 + quad * 4 + r) * 72 + nb * 16 + lrow] = (bf16)p[mt][nb][r];
            asm volatile("s_waitcnt lgkmcnt(0)" ::: "memory");

            #pragma unroll
            for (int ks = 0; ks < 2; ++ks) {
                bf16x8 pf[2];
                #pragma unroll
                for (int mt = 0; mt < 2; ++mt)
                    pf[mt] = *(const bf16x8*)(Pw + (mt * 16 + lrow) * 72 + ks * 32 + quad * 8);
                #pragma unroll
                for (int nb = 0; nb < 4; ++nb) {
                    bf16x8 vf = *(const bf16x8*)(Vs + (nb * 16 + lrow) * 72 + ks * 32 + quad * 8);
                    #pragma unroll
                    for (int mt = 0; mt < 2; ++mt)
                        o_acc[mt][nb] = __builtin_amdgcn_mfma_f32_16x16x32_bf16(pf[mt], vf, o_acc[mt][nb], 0, 0, 0);
                }
            }
        }

        #pragma unroll
        for (int mt = 0; mt < 2; ++mt)
            #pragma unroll
            for (int nb = 0; nb < 4; ++nb)
                #pragma unroll
                for (int r = 0; r < 4; ++r) {
                    int s = qbase + w * 32 + mt * 16 + quad * 4 + r;
                    int hd = nb * 16 + lrow;
                    float v = o_acc[mt][nb][r] / l_i[mt][r];
                    O[((size_t)b * S_ + s) * D_ + h * 64 + hd] = (bf16)v;
                }
        __syncthreads();   // protect LDS before next half re-stages
    }
}

// ---------------- pass 3: output projection GEMM (fp32 out) ----------------
__global__ __launch_bounds__(256) void proj_gemm(
    const bf16* __restrict__ A, const bf16* __restrict__ WpT,
    const float* __restrict__ bp, float* __restrict__ out)
{
    __shared__ bf16 As[128 * 32];
    __shared__ bf16 Bs[128 * 32];

    const int t = threadIdx.x;
    const int lid = t & 63, w = t >> 6;
    const int wm = w & 1, wn = w >> 1;
    const int lrow = lid & 15, quad = lid >> 4;
    const int m0 = blockIdx.y * 128, n0 = blockIdx.x * 128;

    const bf16* Ag = A   + (size_t)m0 * D_;
    const bf16* Bg = WpT + (size_t)n0 * D_;

    f32x4 acc[4][4] = {};

    for (int k0 = 0; k0 < D_; k0 += 32) {
        __syncthreads();
        #pragma unroll
        for (int i = 0; i < 2; ++i) {
            int c = t + i * 256;
            int row = c >> 2, k8 = (c & 3) << 3;
            *(u32x4*)(As + row * 32 + k8) = *(const u32x4*)(Ag + (size_t)row * D_ + k0 + k8);
            *(u32x4*)(Bs + row * 32 + k8) = *(const u32x4*)(Bg + (size_t)row * D_ + k0 + k8);
        }
        __syncthreads();
        bf16x8 a[4], b[4];
        #pragma unroll
        for (int mb = 0; mb < 4; ++mb)
            a[mb] = *(const bf16x8*)(As + (wm * 64 + mb * 16 + lrow) * 32 + quad * 8);
        #pragma unroll
        for (int nb = 0; nb < 4; ++nb)
            b[nb] = *(const bf16x8*)(Bs + (wn * 64 + nb * 16 + lrow) * 32 + quad * 8);
        #pragma unroll
        for (int mb = 0; mb < 4; ++mb)
            #pragma unroll
            for (int nb = 0; nb < 4; ++nb)
                acc[mb][nb] = __builtin_amdgcn_mfma_f32_16x16x32_bf16(a[mb], b[nb], acc[mb][nb], 0, 0, 0);
    }

    #pragma unroll
    for (int mb = 0; mb < 4; ++mb) {
        #pragma unroll
        for (int nb = 0; nb < 4; ++nb) {
            int gn = n0 + wn * 64 + nb * 16 + lrow;
            float bsv = bp[gn];
            #pragma unroll
            for (int r = 0; r < 4; ++r) {
                int gm = m0 + wm * 64 + mb * 16 + quad * 4 + r;
                out[(size_t)gm * D_ + gn] = acc[mb][nb][r] + bsv;
            }
        }
    }
}

// ---------------- launch ----------------
extern "C" void kernel_launch(void* const* d_in, const int* in_sizes, int n_in,
                              void* d_out, int out_size, void* d_ws, size_t ws_size,
                              hipStream_t stream)
{
    const float* x  = (const float*)d_in[0];
    const float* Wq = (const float*)d_in[1];
    const float* bq = (const float*)d_in[2];
    const float* Wk = (const float*)d_in[3];
    const float* bk = (const float*)d_in[4];
    const float* Wv = (const float*)d_in[5];
    const float* bv = (const float*)d_in[6];
    const float* Wp = (const float*)d_in[7];
    const float* bp = (const float*)d_in[8];

    bf16* ws = (bf16*)d_ws;
    const size_t WSZ = (size_t)D_ * D_;        // 1,048,576 elems
    const size_t BIG = (size_t)B_ * S_ * D_;   // 8,388,608 elems
    bf16* WqT = ws;
    bf16* WkT = WqT + WSZ;
    bf16* WvT = WkT + WSZ;
    bf16* WpT = WvT + WSZ;
    bf16* Qb  = WpT + WSZ;
    bf16* Kb  = Qb + BIG;
    bf16* Vb  = Kb + BIG;    // V^T layout [b,h,hd,s]
    bf16* Ab  = Vb + BIG;    // total ~75.5 MB bf16

    transpose_cvt<<<dim3(32, 32, 4), 256, 0, stream>>>(
        Wq, Wk, Wv, Wp, WqT, WkT, WvT, WpT);

    qkv_gemm<<<dim3(8, 64, 3), 256, 0, stream>>>(
        x, WqT, WkT, WvT, bq, bk, bv, Qb, Kb, Vb);

    attn_fwd<<<dim3(8, 64), 256, 0, stream>>>(Qb, Kb, Vb, Ab);

    proj_gemm<<<dim3(8, 64), 256, 0, stream>>>(Ab, WpT, bp, (float*)d_out);
}

// Round 5
// 354.126 us; speedup vs baseline: 1.5795x; 1.1324x over previous
//
#include <hip/hip_runtime.h>

typedef __bf16 bf16;
typedef __attribute__((ext_vector_type(8))) __bf16 bf16x8;
typedef __attribute__((ext_vector_type(4))) float f32x4;
typedef __attribute__((ext_vector_type(4))) unsigned int u32x4;

#define B_ 4
#define S_ 2048
#define D_ 1024
#define H_ 16
#define HD_ 64

#define GLB(p) ((const __attribute__((address_space(1))) void*)(p))
#define LDS(p) ((__attribute__((address_space(3))) void*)(p))

// ---------------- pass 0a: weight transpose+convert (K,N)fp32 -> (N,K)bf16 --
__global__ __launch_bounds__(256) void transpose_cvt(
    const float* __restrict__ W0, const float* __restrict__ W1,
    const float* __restrict__ W2, const float* __restrict__ W3,
    bf16* __restrict__ T0, bf16* __restrict__ T1,
    bf16* __restrict__ T2, bf16* __restrict__ T3)
{
    __shared__ float tile[32][33];
    int z = blockIdx.z;
    const float* W = (z == 0) ? W0 : (z == 1) ? W1 : (z == 2) ? W2 : W3;
    bf16*        T = (z == 0) ? T0 : (z == 1) ? T1 : (z == 2) ? T2 : T3;
    int bx = blockIdx.x * 32, by = blockIdx.y * 32;
    int tx = threadIdx.x & 31, ty = threadIdx.x >> 5;
    #pragma unroll
    for (int j = 0; j < 32; j += 8)
        tile[ty + j][tx] = W[(size_t)(by + ty + j) * D_ + bx + tx];
    __syncthreads();
    #pragma unroll
    for (int j = 0; j < 32; j += 8)
        T[(size_t)(bx + ty + j) * D_ + by + tx] = (bf16)tile[tx][ty + j];
}

// ---------------- pass 0b: X fp32 -> bf16 ----------------
__global__ __launch_bounds__(256) void cvt_x(
    const float* __restrict__ X, bf16* __restrict__ Xb)
{
    size_t i = ((size_t)blockIdx.x * 256 + threadIdx.x) * 8;
    f32x4 a = *(const f32x4*)(X + i);
    f32x4 b = *(const f32x4*)(X + i + 4);
    bf16x8 v;
    #pragma unroll
    for (int j = 0; j < 4; ++j) { v[j] = (bf16)a[j]; v[4 + j] = (bf16)b[j]; }
    *(bf16x8*)(Xb + i) = v;
}

// ---------------- pass 1: fused QKV projection GEMM ----------------
// C(8192x1024) = Xb(bf16) @ W, WT(N,K) bf16 in ws. 128x128 tile, BK=32.
// Staging via global_load_lds width=16 (m97 pattern).
// Epilogue: Q -> (b,h,s,hd) pre-scaled by log2(e)/8; K -> (b,h,s,hd);
// V -> (b,h,hd,s) transposed.
__global__ __launch_bounds__(256) void qkv_gemm(
    const bf16* __restrict__ Xb,
    const bf16* __restrict__ WqT, const bf16* __restrict__ WkT, const bf16* __restrict__ WvT,
    const float* __restrict__ bq, const float* __restrict__ bk, const float* __restrict__ bv,
    bf16* __restrict__ Qo, bf16* __restrict__ Ko, bf16* __restrict__ Vo)
{
    const int z = blockIdx.z;
    const bf16*  WT   = (z == 0) ? WqT : (z == 1) ? WkT : WvT;
    const float* bias = (z == 0) ? bq  : (z == 1) ? bk  : bv;
    bf16*        out  = (z == 0) ? Qo  : (z == 1) ? Ko  : Vo;
    // Q scale: 1/sqrt(64) * log2(e) so attention scores are in exp2 domain
    const float scale = (z == 0) ? 0.18033688011112042f : 1.0f;

    __shared__ bf16 As[128 * 32];
    __shared__ bf16 Bs[128 * 32];

    const int t = threadIdx.x;
    const int lid = t & 63, w = t >> 6;
    const int wm = w & 1, wn = w >> 1;
    const int lrow = lid & 15, quad = lid >> 4;
    const int m0 = blockIdx.y * 128, n0 = blockIdx.x * 128;

    const bf16* Ag = Xb + (size_t)m0 * D_;
    const bf16* Bg = WT + (size_t)n0 * D_;

    // per-thread staging coords: chunk c = t + i*256 -> row, k-offset
    const int row0 = t >> 2, k80 = (t & 3) << 3;          // i = 0
    const int row1 = (t + 256) >> 2;                       // i = 1 (same k80)

    f32x4 acc[4][4] = {};

    for (int k0 = 0; k0 < D_; k0 += 32) {
        __syncthreads();
        __builtin_amdgcn_global_load_lds(GLB(Ag + (size_t)row0 * D_ + k0 + k80),
                                         LDS(As + t * 8), 16, 0, 0);
        __builtin_amdgcn_global_load_lds(GLB(Bg + (size_t)row0 * D_ + k0 + k80),
                                         LDS(Bs + t * 8), 16, 0, 0);
        __builtin_amdgcn_global_load_lds(GLB(Ag + (size_t)row1 * D_ + k0 + k80),
                                         LDS(As + t * 8 + 2048), 16, 0, 0);
        __builtin_amdgcn_global_load_lds(GLB(Bg + (size_t)row1 * D_ + k0 + k80),
                                         LDS(Bs + t * 8 + 2048), 16, 0, 0);
        __syncthreads();
        bf16x8 a[4], b[4];
        #pragma unroll
        for (int mb = 0; mb < 4; ++mb)
            a[mb] = *(const bf16x8*)(As + (wm * 64 + mb * 16 + lrow) * 32 + quad * 8);
        #pragma unroll
        for (int nb = 0; nb < 4; ++nb)
            b[nb] = *(const bf16x8*)(Bs + (wn * 64 + nb * 16 + lrow) * 32 + quad * 8);
        #pragma unroll
        for (int mb = 0; mb < 4; ++mb)
            #pragma unroll
            for (int nb = 0; nb < 4; ++nb)
                acc[mb][nb] = __builtin_amdgcn_mfma_f32_16x16x32_bf16(a[mb], b[nb], acc[mb][nb], 0, 0, 0);
    }

    #pragma unroll
    for (int mb = 0; mb < 4; ++mb) {
        #pragma unroll
        for (int nb = 0; nb < 4; ++nb) {
            int gn = n0 + wn * 64 + nb * 16 + lrow;
            float bsv = bias[gn];
            int h = gn >> 6, hd = gn & 63;
            #pragma unroll
            for (int r = 0; r < 4; ++r) {
                int gm = m0 + wm * 64 + mb * 16 + quad * 4 + r;
                int bb = gm >> 11, s = gm & 2047;
                float v = (acc[mb][nb][r] + bsv) * scale;
                if (z == 2) {
                    // V^T: [b, h, hd, s]
                    out[(((size_t)(bb * H_ + h)) * HD_ + hd) * S_ + s] = (bf16)v;
                } else {
                    // Q/K: [b, h, s, hd]
                    out[(((size_t)(bb * H_ + h)) * S_ + s) * HD_ + hd] = (bf16)v;
                }
            }
        }
    }
}

// ---------------- pass 2: causal flash attention ----------------
// Each block processes TWO 128-query tiles: (15 - blockIdx.x) and blockIdx.x,
// constant work per block. 4 waves x 32 query rows per tile.
// V comes pre-transposed [b,h,hd,s]. Softmax in exp2 domain (Q pre-scaled).
__global__ __launch_bounds__(256) void attn_fwd(
    const bf16* __restrict__ Q, const bf16* __restrict__ K,
    const bf16* __restrict__ Vt, bf16* __restrict__ O)
{
    __shared__ bf16 Ks[64 * 72];        // [key][hd], stride 72
    __shared__ bf16 Vs[64 * 72];        // [hd][key], staged from V^T
    __shared__ bf16 Ps[4 * 32 * 72];    // per-wave P round-trip

    const int bh = blockIdx.y;
    const int t = threadIdx.x, lid = t & 63, w = t >> 6;
    const int lrow = lid & 15, quad = lid >> 4;
    const int b = bh >> 4, h = bh & 15;

    #pragma unroll 1
    for (int half = 0; half < 2; ++half) {
        const int qtile = half ? blockIdx.x : (15 - blockIdx.x);
        const int qbase = qtile * 128;

        // Q fragments: 2 m-tiles x 2 k-frags
        const bf16* Qp = Q + ((size_t)bh * S_ + qbase + w * 32) * HD_;
        bf16x8 qf[2][2];
        #pragma unroll
        for (int mt = 0; mt < 2; ++mt)
            #pragma unroll
            for (int ks = 0; ks < 2; ++ks)
                qf[mt][ks] = *(const bf16x8*)(Qp + (mt * 16 + lrow) * HD_ + ks * 32 + quad * 8);

        f32x4 o_acc[2][4] = {};
        float m_i[2][4], l_i[2][4];
        #pragma unroll
        for (int mt = 0; mt < 2; ++mt)
            #pragma unroll
            for (int r = 0; r < 4; ++r) { m_i[mt][r] = -3.0e4f; l_i[mt][r] = 0.0f; }

        const int ktmax = 2 * qtile + 1;
        for (int kt = 0; kt <= ktmax; ++kt) {
            const bf16* Kp = K  + ((size_t)bh * S_ + kt * 64) * HD_;
            const bf16* Vp = Vt + ((size_t)bh * HD_) * S_ + kt * 64;
            __syncthreads();
            #pragma unroll
            for (int i = 0; i < 2; ++i) {
                int c = t + i * 256;
                int row = c >> 3, c8 = (c & 7) << 3;   // row: key for K, hd for V
                *(u32x4*)(Ks + row * 72 + c8) = *(const u32x4*)(Kp + (size_t)row * HD_ + c8);
                *(u32x4*)(Vs + row * 72 + c8) = *(const u32x4*)(Vp + (size_t)row * S_ + c8);
            }
            __syncthreads();

            // S = Q K^T  (Q pre-scaled into exp2 domain)
            f32x4 sa[2][4] = {};
            #pragma unroll
            for (int ks = 0; ks < 2; ++ks) {
                #pragma unroll
                for (int nb = 0; nb < 4; ++nb) {
                    bf16x8 kf = *(const bf16x8*)(Ks + (nb * 16 + lrow) * 72 + ks * 32 + quad * 8);
                    #pragma unroll
                    for (int mt = 0; mt < 2; ++mt)
                        sa[mt][nb] = __builtin_amdgcn_mfma_f32_16x16x32_bf16(qf[mt][ks], kf, sa[mt][nb], 0, 0, 0);
                }
            }
            if (kt >= 2 * qtile) {  // possibly-diagonal tiles: causal mask
                #pragma unroll
                for (int mt = 0; mt < 2; ++mt)
                    #pragma unroll
                    for (int nb = 0; nb < 4; ++nb) {
                        int key = kt * 64 + nb * 16 + lrow;
                        #pragma unroll
                        for (int r = 0; r < 4; ++r) {
                            int qr = qbase + w * 32 + mt * 16 + quad * 4 + r;
                            if (key > qr) sa[mt][nb][r] = -3.0e4f;
                        }
                    }
            }

            // online softmax (exp2 domain), row = (quad, r)
            float p[2][4][4];
            #pragma unroll
            for (int mt = 0; mt < 2; ++mt) {
                float rm[4], rs[4], al[4];
                #pragma unroll
                for (int r = 0; r < 4; ++r)
                    rm[r] = fmaxf(fmaxf(sa[mt][0][r], sa[mt][1][r]), fmaxf(sa[mt][2][r], sa[mt][3][r]));
                #pragma unroll
                for (int off = 8; off >= 1; off >>= 1)
                    #pragma unroll
                    for (int r = 0; r < 4; ++r)
                        rm[r] = fmaxf(rm[r], __shfl_xor(rm[r], off, 16));
                #pragma unroll
                for (int r = 0; r < 4; ++r) {
                    float mnew = fmaxf(m_i[mt][r], rm[r]);
                    al[r] = exp2f(m_i[mt][r] - mnew);
                    m_i[mt][r] = mnew;
                }
                #pragma unroll
                for (int nb = 0; nb < 4; ++nb)
                    #pragma unroll
                    for (int r = 0; r < 4; ++r)
                        p[mt][nb][r] = exp2f(sa[mt][nb][r] - m_i[mt][r]);
                #pragma unroll
                for (int r = 0; r < 4; ++r)
                    rs[r] = p[mt][0][r] + p[mt][1][r] + p[mt][2][r] + p[mt][3][r];
                #pragma unroll
                for (int off = 8; off >= 1; off >>= 1)
                    #pragma unroll
                    for (int r = 0; r < 4; ++r)
                        rs[r] += __shfl_xor(rs[r], off, 16);
                #pragma unroll
                for (int r = 0; r < 4; ++r)
                    l_i[mt][r] = l_i[mt][r] * al[r] + rs[r];
                #pragma unroll
                for (int nb = 0; nb < 4; ++nb)
                    #pragma unroll
                    for (int r = 0; r < 4; ++r)
                        o_acc[mt][nb][r] *= al[r];
            }

            // P: C-layout -> LDS -> A-layout (wave-private region)
            bf16* Pw = Ps + w * 32 * 72;
            #pragma unroll
            for (int mt = 0; mt < 2; ++mt)
                #pragma unroll
                for (int nb = 0; nb < 4; ++nb)
                    #pragma unroll
                    for (int r = 0; r < 4; ++r)
                        Pw[(mt * 16 + quad * 4 + r) * 72 + nb * 16 + lrow] = (bf16)p[mt][nb][r];
            asm volatile("s_waitcnt lgkmcnt(0)" ::: "memory");

            #pragma unroll
            for (int ks = 0; ks < 2; ++ks) {
                bf16x8 pf[2];
                #pragma unroll
                for (int mt = 0; mt < 2; ++mt)
                    pf[mt] = *(const bf16x8*)(Pw + (mt * 16 + lrow) * 72 + ks * 32 + quad * 8);
                #pragma unroll
                for (int nb = 0; nb < 4; ++nb) {
                    bf16x8 vf = *(const bf16x8*)(Vs + (nb * 16 + lrow) * 72 + ks * 32 + quad * 8);
                    #pragma unroll
                    for (int mt = 0; mt < 2; ++mt)
                        o_acc[mt][nb] = __builtin_amdgcn_mfma_f32_16x16x32_bf16(pf[mt], vf, o_acc[mt][nb], 0, 0, 0);
                }
            }
        }

        #pragma unroll
        for (int mt = 0; mt < 2; ++mt)
            #pragma unroll
            for (int nb = 0; nb < 4; ++nb)
                #pragma unroll
                for (int r = 0; r < 4; ++r) {
                    int s = qbase + w * 32 + mt * 16 + quad * 4 + r;
                    int hd = nb * 16 + lrow;
                    float v = o_acc[mt][nb][r] / l_i[mt][r];
                    O[((size_t)b * S_ + s) * D_ + h * 64 + hd] = (bf16)v;
                }
        __syncthreads();   // protect LDS before next half re-stages
    }
}

// ---------------- pass 3: output projection GEMM (fp32 out) ----------------
__global__ __launch_bounds__(256) void proj_gemm(
    const bf16* __restrict__ A, const bf16* __restrict__ WpT,
    const float* __restrict__ bp, float* __restrict__ out)
{
    __shared__ bf16 As[128 * 32];
    __shared__ bf16 Bs[128 * 32];

    const int t = threadIdx.x;
    const int lid = t & 63, w = t >> 6;
    const int wm = w & 1, wn = w >> 1;
    const int lrow = lid & 15, quad = lid >> 4;
    const int m0 = blockIdx.y * 128, n0 = blockIdx.x * 128;

    const bf16* Ag = A   + (size_t)m0 * D_;
    const bf16* Bg = WpT + (size_t)n0 * D_;

    const int row0 = t >> 2, k80 = (t & 3) << 3;
    const int row1 = (t + 256) >> 2;

    f32x4 acc[4][4] = {};

    for (int k0 = 0; k0 < D_; k0 += 32) {
        __syncthreads();
        __builtin_amdgcn_global_load_lds(GLB(Ag + (size_t)row0 * D_ + k0 + k80),
                                         LDS(As + t * 8), 16, 0, 0);
        __builtin_amdgcn_global_load_lds(GLB(Bg + (size_t)row0 * D_ + k0 + k80),
                                         LDS(Bs + t * 8), 16, 0, 0);
        __builtin_amdgcn_global_load_lds(GLB(Ag + (size_t)row1 * D_ + k0 + k80),
                                         LDS(As + t * 8 + 2048), 16, 0, 0);
        __builtin_amdgcn_global_load_lds(GLB(Bg + (size_t)row1 * D_ + k0 + k80),
                                         LDS(Bs + t * 8 + 2048), 16, 0, 0);
        __syncthreads();
        bf16x8 a[4], b[4];
        #pragma unroll
        for (int mb = 0; mb < 4; ++mb)
            a[mb] = *(const bf16x8*)(As + (wm * 64 + mb * 16 + lrow) * 32 + quad * 8);
        #pragma unroll
        for (int nb = 0; nb < 4; ++nb)
            b[nb] = *(const bf16x8*)(Bs + (wn * 64 + nb * 16 + lrow) * 32 + quad * 8);
        #pragma unroll
        for (int mb = 0; mb < 4; ++mb)
            #pragma unroll
            for (int nb = 0; nb < 4; ++nb)
                acc[mb][nb] = __builtin_amdgcn_mfma_f32_16x16x32_bf16(a[mb], b[nb], acc[mb][nb], 0, 0, 0);
    }

    #pragma unroll
    for (int mb = 0; mb < 4; ++mb) {
        #pragma unroll
        for (int nb = 0; nb < 4; ++nb) {
            int gn = n0 + wn * 64 + nb * 16 + lrow;
            float bsv = bp[gn];
            #pragma unroll
            for (int r = 0; r < 4; ++r) {
                int gm = m0 + wm * 64 + mb * 16 + quad * 4 + r;
                out[(size_t)gm * D_ + gn] = acc[mb][nb][r] + bsv;
            }
        }
    }
}

// ---------------- launch ----------------
extern "C" void kernel_launch(void* const* d_in, const int* in_sizes, int n_in,
                              void* d_out, int out_size, void* d_ws, size_t ws_size,
                              hipStream_t stream)
{
    const float* x  = (const float*)d_in[0];
    const float* Wq = (const float*)d_in[1];
    const float* bq = (const float*)d_in[2];
    const float* Wk = (const float*)d_in[3];
    const float* bk = (const float*)d_in[4];
    const float* Wv = (const float*)d_in[5];
    const float* bv = (const float*)d_in[6];
    const float* Wp = (const float*)d_in[7];
    const float* bp = (const float*)d_in[8];

    bf16* ws = (bf16*)d_ws;
    const size_t WSZ = (size_t)D_ * D_;        // 1,048,576 elems
    const size_t BIG = (size_t)B_ * S_ * D_;   // 8,388,608 elems
    bf16* WqT = ws;
    bf16* WkT = WqT + WSZ;
    bf16* WvT = WkT + WSZ;
    bf16* WpT = WvT + WSZ;
    bf16* Qb  = WpT + WSZ;
    bf16* Kb  = Qb + BIG;
    bf16* Vb  = Kb + BIG;    // V^T layout [b,h,hd,s]
    bf16* Ab  = Vb + BIG;    // X(bf16) during qkv, then attention output

    transpose_cvt<<<dim3(32, 32, 4), 256, 0, stream>>>(
        Wq, Wk, Wv, Wp, WqT, WkT, WvT, WpT);

    cvt_x<<<dim3(4096), 256, 0, stream>>>(x, Ab);

    qkv_gemm<<<dim3(8, 64, 3), 256, 0, stream>>>(
        Ab, WqT, WkT, WvT, bq, bk, bv, Qb, Kb, Vb);

    attn_fwd<<<dim3(8, 64), 256, 0, stream>>>(Qb, Kb, Vb, Ab);

    proj_gemm<<<dim3(8, 64), 256, 0, stream>>>(Ab, WpT, bp, (float*)d_out);
}

// Round 6
// 319.552 us; speedup vs baseline: 1.7503x; 1.1082x over previous
//
#include <hip/hip_runtime.h>

typedef __bf16 bf16;
typedef __attribute__((ext_vector_type(4))) __bf16 bf16x4;
typedef __attribute__((ext_vector_type(8))) __bf16 bf16x8;
typedef __attribute__((ext_vector_type(4))) float f32x4;
typedef __attribute__((ext_vector_type(4))) unsigned int u32x4;

#define B_ 4
#define S_ 2048
#define D_ 1024
#define H_ 16
#define HD_ 64

#define GLB(p) ((const __attribute__((address_space(1))) void*)(p))
#define LDS(p) ((__attribute__((address_space(3))) void*)(p))

// ---------------- pass 0a: weight transpose+convert (K,N)fp32 -> (N,K)bf16 --
__global__ __launch_bounds__(256) void transpose_cvt(
    const float* __restrict__ W0, const float* __restrict__ W1,
    const float* __restrict__ W2, const float* __restrict__ W3,
    bf16* __restrict__ T0, bf16* __restrict__ T1,
    bf16* __restrict__ T2, bf16* __restrict__ T3)
{
    __shared__ float tile[32][33];
    int z = blockIdx.z;
    const float* W = (z == 0) ? W0 : (z == 1) ? W1 : (z == 2) ? W2 : W3;
    bf16*        T = (z == 0) ? T0 : (z == 1) ? T1 : (z == 2) ? T2 : T3;
    int bx = blockIdx.x * 32, by = blockIdx.y * 32;
    int tx = threadIdx.x & 31, ty = threadIdx.x >> 5;
    #pragma unroll
    for (int j = 0; j < 32; j += 8)
        tile[ty + j][tx] = W[(size_t)(by + ty + j) * D_ + bx + tx];
    __syncthreads();
    #pragma unroll
    for (int j = 0; j < 32; j += 8)
        T[(size_t)(bx + ty + j) * D_ + by + tx] = (bf16)tile[tx][ty + j];
}

// ---------------- pass 0b: X fp32 -> bf16 ----------------
__global__ __launch_bounds__(256) void cvt_x(
    const float* __restrict__ X, bf16* __restrict__ Xb)
{
    size_t i = ((size_t)blockIdx.x * 256 + threadIdx.x) * 8;
    f32x4 a = *(const f32x4*)(X + i);
    f32x4 b = *(const f32x4*)(X + i + 4);
    bf16x8 v;
    #pragma unroll
    for (int j = 0; j < 4; ++j) { v[j] = (bf16)a[j]; v[4 + j] = (bf16)b[j]; }
    *(bf16x8*)(Xb + i) = v;
}

// ---------------- pass 1: fused QKV projection GEMM ----------------
// C(8192x1024) = Xb(bf16) @ W, WT(N,K) bf16 in ws. 128x128 tile, BK=32.
// Staging via global_load_lds width=16. Epilogue: Q -> (b,h,s,hd) pre-scaled
// by log2(e)/8; K -> (b,h,s,hd); V -> (b,h,hd,s) transposed (packed stores).
__global__ __launch_bounds__(256) void qkv_gemm(
    const bf16* __restrict__ Xb,
    const bf16* __restrict__ WqT, const bf16* __restrict__ WkT, const bf16* __restrict__ WvT,
    const float* __restrict__ bq, const float* __restrict__ bk, const float* __restrict__ bv,
    bf16* __restrict__ Qo, bf16* __restrict__ Ko, bf16* __restrict__ Vo)
{
    const int z = blockIdx.z;
    const bf16*  WT   = (z == 0) ? WqT : (z == 1) ? WkT : WvT;
    const float* bias = (z == 0) ? bq  : (z == 1) ? bk  : bv;
    bf16*        out  = (z == 0) ? Qo  : (z == 1) ? Ko  : Vo;
    const float scale = (z == 0) ? 0.18033688011112042f : 1.0f;

    __shared__ bf16 As[128 * 32];
    __shared__ bf16 Bs[128 * 32];

    const int t = threadIdx.x;
    const int lid = t & 63, w = t >> 6;
    const int wm = w & 1, wn = w >> 1;
    const int lrow = lid & 15, quad = lid >> 4;
    const int m0 = blockIdx.y * 128, n0 = blockIdx.x * 128;

    const bf16* Ag = Xb + (size_t)m0 * D_;
    const bf16* Bg = WT + (size_t)n0 * D_;

    const int row0 = t >> 2, k80 = (t & 3) << 3;
    const int row1 = (t + 256) >> 2;

    f32x4 acc[4][4] = {};

    for (int k0 = 0; k0 < D_; k0 += 32) {
        __syncthreads();
        __builtin_amdgcn_global_load_lds(GLB(Ag + (size_t)row0 * D_ + k0 + k80),
                                         LDS(As + t * 8), 16, 0, 0);
        __builtin_amdgcn_global_load_lds(GLB(Bg + (size_t)row0 * D_ + k0 + k80),
                                         LDS(Bs + t * 8), 16, 0, 0);
        __builtin_amdgcn_global_load_lds(GLB(Ag + (size_t)row1 * D_ + k0 + k80),
                                         LDS(As + t * 8 + 2048), 16, 0, 0);
        __builtin_amdgcn_global_load_lds(GLB(Bg + (size_t)row1 * D_ + k0 + k80),
                                         LDS(Bs + t * 8 + 2048), 16, 0, 0);
        __syncthreads();
        bf16x8 a[4], b[4];
        #pragma unroll
        for (int mb = 0; mb < 4; ++mb)
            a[mb] = *(const bf16x8*)(As + (wm * 64 + mb * 16 + lrow) * 32 + quad * 8);
        #pragma unroll
        for (int nb = 0; nb < 4; ++nb)
            b[nb] = *(const bf16x8*)(Bs + (wn * 64 + nb * 16 + lrow) * 32 + quad * 8);
        #pragma unroll
        for (int mb = 0; mb < 4; ++mb)
            #pragma unroll
            for (int nb = 0; nb < 4; ++nb)
                acc[mb][nb] = __builtin_amdgcn_mfma_f32_16x16x32_bf16(a[mb], b[nb], acc[mb][nb], 0, 0, 0);
    }

    #pragma unroll
    for (int mb = 0; mb < 4; ++mb) {
        #pragma unroll
        for (int nb = 0; nb < 4; ++nb) {
            int gn = n0 + wn * 64 + nb * 16 + lrow;
            float bsv = bias[gn];
            int h = gn >> 6, hd = gn & 63;
            int gm0 = m0 + wm * 64 + mb * 16 + quad * 4;
            int bb = gm0 >> 11, s0 = gm0 & 2047;
            if (z == 2) {
                // V^T: [b, h, hd, s] — 4 consecutive s, packed 8B store
                bf16x4 pk;
                #pragma unroll
                for (int r = 0; r < 4; ++r)
                    pk[r] = (bf16)(acc[mb][nb][r] + bsv);
                *(bf16x4*)(out + (((size_t)(bb * H_ + h)) * HD_ + hd) * S_ + s0) = pk;
            } else {
                // Q/K: [b, h, s, hd]
                #pragma unroll
                for (int r = 0; r < 4; ++r) {
                    float v = (acc[mb][nb][r] + bsv) * scale;
                    out[(((size_t)(bb * H_ + h)) * S_ + (s0 + r)) * HD_ + hd] = (bf16)v;
                }
            }
        }
    }
}

// ---------------- pass 2: causal flash attention (S-transposed scheme) -----
// Each block: two 128-query tiles (15-bx, bx) for constant work. 4 waves x
// 32 queries (2 m-tiles of 16). S^T = mfma(K_frag, Q_frag): query on C-column
// (lane&15), keys in-lane -> softmax = in-lane tree + 2 shuffles. P packed
// b64 to LDS; O^T = mfma(V^T_frag, P_frag). V pre-transposed [b,h,hd,s].
__global__ __launch_bounds__(256) void attn_fwd(
    const bf16* __restrict__ Q, const bf16* __restrict__ K,
    const bf16* __restrict__ Vt, bf16* __restrict__ O)
{
    __shared__ bf16 Ks[64 * 72];        // [key][hd], stride 72
    __shared__ bf16 Vs[64 * 72];        // [hd][key], staged from V^T
    __shared__ bf16 Ps[4 * 32 * 72];    // per-wave P [query][key], stride 72

    const int bh = blockIdx.y;
    const int t = threadIdx.x, lid = t & 63, w = t >> 6;
    const int lrow = lid & 15, quad = lid >> 4;
    const int b = bh >> 4, h = bh & 15;

    #pragma unroll 1
    for (int half = 0; half < 2; ++half) {
        const int qtile = half ? blockIdx.x : (15 - blockIdx.x);
        const int qbase = qtile * 128;

        // Q fragments (B-operand): lane n=query=lrow, k=hd in-lane
        const bf16* Qp = Q + ((size_t)bh * S_ + qbase + w * 32) * HD_;
        bf16x8 qf[2][2];
        #pragma unroll
        for (int mt = 0; mt < 2; ++mt)
            #pragma unroll
            for (int ks = 0; ks < 2; ++ks)
                qf[mt][ks] = *(const bf16x8*)(Qp + (mt * 16 + lrow) * HD_ + ks * 32 + quad * 8);

        f32x4 o_acc[2][4] = {};           // O^T: [mt][hd-block], col=query
        float m_i[2], l_i[2];
        #pragma unroll
        for (int mt = 0; mt < 2; ++mt) { m_i[mt] = -3.0e4f; l_i[mt] = 0.0f; }

        const int ktmax = 2 * qtile + 1;
        for (int kt = 0; kt <= ktmax; ++kt) {
            const bf16* Kp = K  + ((size_t)bh * S_ + kt * 64) * HD_;
            const bf16* Vp = Vt + ((size_t)bh * HD_) * S_ + kt * 64;
            __syncthreads();
            #pragma unroll
            for (int i = 0; i < 2; ++i) {
                int c = t + i * 256;
                int row = c >> 3, c8 = (c & 7) << 3;   // row: key for K, hd for V
                *(u32x4*)(Ks + row * 72 + c8) = *(const u32x4*)(Kp + (size_t)row * HD_ + c8);
                *(u32x4*)(Vs + row * 72 + c8) = *(const u32x4*)(Vp + (size_t)row * S_ + c8);
            }
            __syncthreads();

            // S^T = K Q^T: D[m=key][n=query]; lane: query=lrow, key=nb*16+quad*4+r
            f32x4 sa[2][4] = {};
            #pragma unroll
            for (int ks = 0; ks < 2; ++ks) {
                #pragma unroll
                for (int nb = 0; nb < 4; ++nb) {
                    bf16x8 kf = *(const bf16x8*)(Ks + (nb * 16 + lrow) * 72 + ks * 32 + quad * 8);
                    #pragma unroll
                    for (int mt = 0; mt < 2; ++mt)
                        sa[mt][nb] = __builtin_amdgcn_mfma_f32_16x16x32_bf16(kf, qf[mt][ks], sa[mt][nb], 0, 0, 0);
                }
            }
            if (kt >= 2 * qtile) {  // possibly-diagonal tiles: causal mask
                #pragma unroll
                for (int mt = 0; mt < 2; ++mt) {
                    int q = qbase + w * 32 + mt * 16 + lrow;
                    #pragma unroll
                    for (int nb = 0; nb < 4; ++nb) {
                        int key = kt * 64 + nb * 16 + quad * 4;
                        #pragma unroll
                        for (int r = 0; r < 4; ++r)
                            if (key + r > q) sa[mt][nb][r] = -3.0e4f;
                    }
                }
            }

            // online softmax (exp2 domain): in-lane over 16 keys + 2 shuffles
            float p[2][4][4];
            #pragma unroll
            for (int mt = 0; mt < 2; ++mt) {
                float rm = sa[mt][0][0];
                #pragma unroll
                for (int nb = 0; nb < 4; ++nb)
                    #pragma unroll
                    for (int r = 0; r < 4; ++r)
                        rm = fmaxf(rm, sa[mt][nb][r]);
                rm = fmaxf(rm, __shfl_xor(rm, 16));
                rm = fmaxf(rm, __shfl_xor(rm, 32));
                float mnew = fmaxf(m_i[mt], rm);
                float al = exp2f(m_i[mt] - mnew);
                m_i[mt] = mnew;
                float rs = 0.0f;
                #pragma unroll
                for (int nb = 0; nb < 4; ++nb)
                    #pragma unroll
                    for (int r = 0; r < 4; ++r) {
                        float e = exp2f(sa[mt][nb][r] - mnew);
                        p[mt][nb][r] = e;
                        rs += e;
                    }
                rs += __shfl_xor(rs, 16);
                rs += __shfl_xor(rs, 32);
                l_i[mt] = l_i[mt] * al + rs;
                #pragma unroll
                for (int nb = 0; nb < 4; ++nb)
                    #pragma unroll
                    for (int r = 0; r < 4; ++r)
                        o_acc[mt][nb][r] *= al;
            }

            // P -> LDS [query][key], packed b64 (keys quad*4..quad*4+3)
            bf16* Pw = Ps + w * 32 * 72;
            #pragma unroll
            for (int mt = 0; mt < 2; ++mt)
                #pragma unroll
                for (int nb = 0; nb < 4; ++nb) {
                    bf16x4 pk;
                    #pragma unroll
                    for (int r = 0; r < 4; ++r)
                        pk[r] = (bf16)p[mt][nb][r];
                    *(bf16x4*)(Pw + (mt * 16 + lrow) * 72 + nb * 16 + quad * 4) = pk;
                }
            asm volatile("s_waitcnt lgkmcnt(0)" ::: "memory");

            // O^T += V^T P^T: A=V^T[hd][key], B=P[query][key]
            #pragma unroll
            for (int ks = 0; ks < 2; ++ks) {
                bf16x8 pf[2];
                #pragma unroll
                for (int mt = 0; mt < 2; ++mt)
                    pf[mt] = *(const bf16x8*)(Pw + (mt * 16 + lrow) * 72 + ks * 32 + quad * 8);
                #pragma unroll
                for (int nb = 0; nb < 4; ++nb) {
                    bf16x8 vf = *(const bf16x8*)(Vs + (nb * 16 + lrow) * 72 + ks * 32 + quad * 8);
                    #pragma unroll
                    for (int mt = 0; mt < 2; ++mt)
                        o_acc[mt][nb] = __builtin_amdgcn_mfma_f32_16x16x32_bf16(vf, pf[mt], o_acc[mt][nb], 0, 0, 0);
                }
            }
        }

        // epilogue: O^T regs -> O[b,s,d]; lane: s=query fixed, 4 consecutive hd
        #pragma unroll
        for (int mt = 0; mt < 2; ++mt) {
            float inv = 1.0f / l_i[mt];
            int s = qbase + w * 32 + mt * 16 + lrow;
            #pragma unroll
            for (int nb = 0; nb < 4; ++nb) {
                bf16x4 pk;
                #pragma unroll
                for (int r = 0; r < 4; ++r)
                    pk[r] = (bf16)(o_acc[mt][nb][r] * inv);
                *(bf16x4*)(O + ((size_t)b * S_ + s) * D_ + h * 64 + nb * 16 + quad * 4) = pk;
            }
        }
        __syncthreads();   // protect LDS before next half re-stages
    }
}

// ---------------- pass 3: output projection GEMM (fp32 out) ----------------
__global__ __launch_bounds__(256) void proj_gemm(
    const bf16* __restrict__ A, const bf16* __restrict__ WpT,
    const float* __restrict__ bp, float* __restrict__ out)
{
    __shared__ bf16 As[128 * 32];
    __shared__ bf16 Bs[128 * 32];

    const int t = threadIdx.x;
    const int lid = t & 63, w = t >> 6;
    const int wm = w & 1, wn = w >> 1;
    const int lrow = lid & 15, quad = lid >> 4;
    const int m0 = blockIdx.y * 128, n0 = blockIdx.x * 128;

    const bf16* Ag = A   + (size_t)m0 * D_;
    const bf16* Bg = WpT + (size_t)n0 * D_;

    const int row0 = t >> 2, k80 = (t & 3) << 3;
    const int row1 = (t + 256) >> 2;

    f32x4 acc[4][4] = {};

    for (int k0 = 0; k0 < D_; k0 += 32) {
        __syncthreads();
        __builtin_amdgcn_global_load_lds(GLB(Ag + (size_t)row0 * D_ + k0 + k80),
                                         LDS(As + t * 8), 16, 0, 0);
        __builtin_amdgcn_global_load_lds(GLB(Bg + (size_t)row0 * D_ + k0 + k80),
                                         LDS(Bs + t * 8), 16, 0, 0);
        __builtin_amdgcn_global_load_lds(GLB(Ag + (size_t)row1 * D_ + k0 + k80),
                                         LDS(As + t * 8 + 2048), 16, 0, 0);
        __builtin_amdgcn_global_load_lds(GLB(Bg + (size_t)row1 * D_ + k0 + k80),
                                         LDS(Bs + t * 8 + 2048), 16, 0, 0);
        __syncthreads();
        bf16x8 a[4], b[4];
        #pragma unroll
        for (int mb = 0; mb < 4; ++mb)
            a[mb] = *(const bf16x8*)(As + (wm * 64 + mb * 16 + lrow) * 32 + quad * 8);
        #pragma unroll
        for (int nb = 0; nb < 4; ++nb)
            b[nb] = *(const bf16x8*)(Bs + (wn * 64 + nb * 16 + lrow) * 32 + quad * 8);
        #pragma unroll
        for (int mb = 0; mb < 4; ++mb)
            #pragma unroll
            for (int nb = 0; nb < 4; ++nb)
                acc[mb][nb] = __builtin_amdgcn_mfma_f32_16x16x32_bf16(a[mb], b[nb], acc[mb][nb], 0, 0, 0);
    }

    #pragma unroll
    for (int mb = 0; mb < 4; ++mb) {
        #pragma unroll
        for (int nb = 0; nb < 4; ++nb) {
            int gn = n0 + wn * 64 + nb * 16 + lrow;
            float bsv = bp[gn];
            #pragma unroll
            for (int r = 0; r < 4; ++r) {
                int gm = m0 + wm * 64 + mb * 16 + quad * 4 + r;
                out[(size_t)gm * D_ + gn] = acc[mb][nb][r] + bsv;
            }
        }
    }
}

// ---------------- launch ----------------
extern "C" void kernel_launch(void* const* d_in, const int* in_sizes, int n_in,
                              void* d_out, int out_size, void* d_ws, size_t ws_size,
                              hipStream_t stream)
{
    const float* x  = (const float*)d_in[0];
    const float* Wq = (const float*)d_in[1];
    const float* bq = (const float*)d_in[2];
    const float* Wk = (const float*)d_in[3];
    const float* bk = (const float*)d_in[4];
    const float* Wv = (const float*)d_in[5];
    const float* bv = (const float*)d_in[6];
    const float* Wp = (const float*)d_in[7];
    const float* bp = (const float*)d_in[8];

    bf16* ws = (bf16*)d_ws;
    const size_t WSZ = (size_t)D_ * D_;        // 1,048,576 elems
    const size_t BIG = (size_t)B_ * S_ * D_;   // 8,388,608 elems
    bf16* WqT = ws;
    bf16* WkT = WqT + WSZ;
    bf16* WvT = WkT + WSZ;
    bf16* WpT = WvT + WSZ;
    bf16* Qb  = WpT + WSZ;
    bf16* Kb  = Qb + BIG;
    bf16* Vb  = Kb + BIG;    // V^T layout [b,h,hd,s]
    bf16* Ab  = Vb + BIG;    // X(bf16) during qkv, then attention output

    transpose_cvt<<<dim3(32, 32, 4), 256, 0, stream>>>(
        Wq, Wk, Wv, Wp, WqT, WkT, WvT, WpT);

    cvt_x<<<dim3(4096), 256, 0, stream>>>(x, Ab);

    qkv_gemm<<<dim3(8, 64, 3), 256, 0, stream>>>(
        Ab, WqT, WkT, WvT, bq, bk, bv, Qb, Kb, Vb);

    attn_fwd<<<dim3(8, 64), 256, 0, stream>>>(Qb, Kb, Vb, Ab);

    proj_gemm<<<dim3(8, 64), 256, 0, stream>>>(Ab, WpT, bp, (float*)d_out);
}

// Round 7
// 291.442 us; speedup vs baseline: 1.9192x; 1.0965x over previous
//
#include <hip/hip_runtime.h>

typedef __bf16 bf16;
typedef __attribute__((ext_vector_type(4))) __bf16 bf16x4;
typedef __attribute__((ext_vector_type(8))) __bf16 bf16x8;
typedef __attribute__((ext_vector_type(4))) float f32x4;
typedef __attribute__((ext_vector_type(4))) unsigned int u32x4;

#define B_ 4
#define S_ 2048
#define D_ 1024
#define H_ 16
#define HD_ 64

#define GLB(p) ((const __attribute__((address_space(1))) void*)(p))
#define LDS(p) ((__attribute__((address_space(3))) void*)(p))

// ---------------- pass 0a: weight transpose+convert (K,N)fp32 -> (N,K)bf16 --
__global__ __launch_bounds__(256) void transpose_cvt(
    const float* __restrict__ W0, const float* __restrict__ W1,
    const float* __restrict__ W2, const float* __restrict__ W3,
    bf16* __restrict__ T0, bf16* __restrict__ T1,
    bf16* __restrict__ T2, bf16* __restrict__ T3)
{
    __shared__ float tile[32][33];
    int z = blockIdx.z;
    const float* W = (z == 0) ? W0 : (z == 1) ? W1 : (z == 2) ? W2 : W3;
    bf16*        T = (z == 0) ? T0 : (z == 1) ? T1 : (z == 2) ? T2 : T3;
    int bx = blockIdx.x * 32, by = blockIdx.y * 32;
    int tx = threadIdx.x & 31, ty = threadIdx.x >> 5;
    #pragma unroll
    for (int j = 0; j < 32; j += 8)
        tile[ty + j][tx] = W[(size_t)(by + ty + j) * D_ + bx + tx];
    __syncthreads();
    #pragma unroll
    for (int j = 0; j < 32; j += 8)
        T[(size_t)(bx + ty + j) * D_ + by + tx] = (bf16)tile[tx][ty + j];
}

// ---------------- pass 0b: X fp32 -> bf16 ----------------
__global__ __launch_bounds__(256) void cvt_x(
    const float* __restrict__ X, bf16* __restrict__ Xb)
{
    size_t i = ((size_t)blockIdx.x * 256 + threadIdx.x) * 8;
    f32x4 a = *(const f32x4*)(X + i);
    f32x4 b = *(const f32x4*)(X + i + 4);
    bf16x8 v;
    #pragma unroll
    for (int j = 0; j < 4; ++j) { v[j] = (bf16)a[j]; v[4 + j] = (bf16)b[j]; }
    *(bf16x8*)(Xb + i) = v;
}

// ---------------- pass 1: fused QKV projection GEMM ----------------
// C(8192x1024) = Xb(bf16) @ W, WT(N,K) bf16 in ws. 128x128 tile, BK=32.
// Staging via global_load_lds width=16. Epilogue: Q -> (b,h,s,hd) pre-scaled
// by log2(e)/8; K -> (b,h,s,hd); V -> (b,h,hd,s) transposed (packed stores).
__global__ __launch_bounds__(256) void qkv_gemm(
    const bf16* __restrict__ Xb,
    const bf16* __restrict__ WqT, const bf16* __restrict__ WkT, const bf16* __restrict__ WvT,
    const float* __restrict__ bq, const float* __restrict__ bk, const float* __restrict__ bv,
    bf16* __restrict__ Qo, bf16* __restrict__ Ko, bf16* __restrict__ Vo)
{
    const int z = blockIdx.z;
    const bf16*  WT   = (z == 0) ? WqT : (z == 1) ? WkT : WvT;
    const float* bias = (z == 0) ? bq  : (z == 1) ? bk  : bv;
    bf16*        out  = (z == 0) ? Qo  : (z == 1) ? Ko  : Vo;
    const float scale = (z == 0) ? 0.18033688011112042f : 1.0f;

    __shared__ bf16 As[128 * 32];
    __shared__ bf16 Bs[128 * 32];

    const int t = threadIdx.x;
    const int lid = t & 63, w = t >> 6;
    const int wm = w & 1, wn = w >> 1;
    const int lrow = lid & 15, quad = lid >> 4;
    const int m0 = blockIdx.y * 128, n0 = blockIdx.x * 128;

    const bf16* Ag = Xb + (size_t)m0 * D_;
    const bf16* Bg = WT + (size_t)n0 * D_;

    const int row0 = t >> 2, k80 = (t & 3) << 3;
    const int row1 = (t + 256) >> 2;

    f32x4 acc[4][4] = {};

    for (int k0 = 0; k0 < D_; k0 += 32) {
        __syncthreads();
        __builtin_amdgcn_global_load_lds(GLB(Ag + (size_t)row0 * D_ + k0 + k80),
                                         LDS(As + t * 8), 16, 0, 0);
        __builtin_amdgcn_global_load_lds(GLB(Bg + (size_t)row0 * D_ + k0 + k80),
                                         LDS(Bs + t * 8), 16, 0, 0);
        __builtin_amdgcn_global_load_lds(GLB(Ag + (size_t)row1 * D_ + k0 + k80),
                                         LDS(As + t * 8 + 2048), 16, 0, 0);
        __builtin_amdgcn_global_load_lds(GLB(Bg + (size_t)row1 * D_ + k0 + k80),
                                         LDS(Bs + t * 8 + 2048), 16, 0, 0);
        __syncthreads();
        bf16x8 a[4], b[4];
        #pragma unroll
        for (int mb = 0; mb < 4; ++mb)
            a[mb] = *(const bf16x8*)(As + (wm * 64 + mb * 16 + lrow) * 32 + quad * 8);
        #pragma unroll
        for (int nb = 0; nb < 4; ++nb)
            b[nb] = *(const bf16x8*)(Bs + (wn * 64 + nb * 16 + lrow) * 32 + quad * 8);
        #pragma unroll
        for (int mb = 0; mb < 4; ++mb)
            #pragma unroll
            for (int nb = 0; nb < 4; ++nb)
                acc[mb][nb] = __builtin_amdgcn_mfma_f32_16x16x32_bf16(a[mb], b[nb], acc[mb][nb], 0, 0, 0);
    }

    #pragma unroll
    for (int mb = 0; mb < 4; ++mb) {
        #pragma unroll
        for (int nb = 0; nb < 4; ++nb) {
            int gn = n0 + wn * 64 + nb * 16 + lrow;
            float bsv = bias[gn];
            int h = gn >> 6, hd = gn & 63;
            int gm0 = m0 + wm * 64 + mb * 16 + quad * 4;
            int bb = gm0 >> 11, s0 = gm0 & 2047;
            if (z == 2) {
                // V^T: [b, h, hd, s] — 4 consecutive s, packed 8B store
                bf16x4 pk;
                #pragma unroll
                for (int r = 0; r < 4; ++r)
                    pk[r] = (bf16)(acc[mb][nb][r] + bsv);
                *(bf16x4*)(out + (((size_t)(bb * H_ + h)) * HD_ + hd) * S_ + s0) = pk;
            } else {
                // Q/K: [b, h, s, hd]
                #pragma unroll
                for (int r = 0; r < 4; ++r) {
                    float v = (acc[mb][nb][r] + bsv) * scale;
                    out[(((size_t)(bb * H_ + h)) * S_ + (s0 + r)) * HD_ + hd] = (bf16)v;
                }
            }
        }
    }
}

// ---------------- pass 2: causal flash attention (S-transposed scheme) -----
// 64-query tiles (32 qtiles). Each block: pair (31-bx, bx) -> constant 33
// key-tile units/block; grid (16,64) = 1024 blocks = 4 blocks/CU for latency
// hiding. 4 waves x 16 queries. S^T = mfma(K_frag, Q_frag): query on C-column
// (lane&15), keys in-lane -> softmax = in-lane tree + 2 shuffles. P packed
// b64 to LDS; O^T = mfma(V^T_frag, P_frag). V pre-transposed [b,h,hd,s].
__global__ __launch_bounds__(256) void attn_fwd(
    const bf16* __restrict__ Q, const bf16* __restrict__ K,
    const bf16* __restrict__ Vt, bf16* __restrict__ O)
{
    __shared__ bf16 Ks[64 * 72];        // [key][hd], stride 72
    __shared__ bf16 Vs[64 * 72];        // [hd][key], staged from V^T
    __shared__ bf16 Ps[4 * 16 * 72];    // per-wave P [query][key], stride 72

    const int bh = blockIdx.y;
    const int t = threadIdx.x, lid = t & 63, w = t >> 6;
    const int lrow = lid & 15, quad = lid >> 4;
    const int b = bh >> 4, h = bh & 15;

    #pragma unroll 1
    for (int half = 0; half < 2; ++half) {
        const int qtile = half ? blockIdx.x : (31 - blockIdx.x);
        const int qbase = qtile * 64;

        // Q fragments (B-operand): lane n=query=lrow, k=hd in-lane
        const bf16* Qp = Q + ((size_t)bh * S_ + qbase + w * 16) * HD_;
        bf16x8 qf[2];
        #pragma unroll
        for (int ks = 0; ks < 2; ++ks)
            qf[ks] = *(const bf16x8*)(Qp + lrow * HD_ + ks * 32 + quad * 8);

        f32x4 o_acc[4] = {};              // O^T: [hd-block], col=query
        float m_i = -3.0e4f, l_i = 0.0f;

        for (int kt = 0; kt <= qtile; ++kt) {
            const bf16* Kp = K  + ((size_t)bh * S_ + kt * 64) * HD_;
            const bf16* Vp = Vt + ((size_t)bh * HD_) * S_ + kt * 64;
            __syncthreads();
            #pragma unroll
            for (int i = 0; i < 2; ++i) {
                int c = t + i * 256;
                int row = c >> 3, c8 = (c & 7) << 3;   // row: key for K, hd for V
                *(u32x4*)(Ks + row * 72 + c8) = *(const u32x4*)(Kp + (size_t)row * HD_ + c8);
                *(u32x4*)(Vs + row * 72 + c8) = *(const u32x4*)(Vp + (size_t)row * S_ + c8);
            }
            __syncthreads();

            // S^T = K Q^T: D[m=key][n=query]; lane: query=lrow, key=nb*16+quad*4+r
            f32x4 sa[4] = {};
            #pragma unroll
            for (int ks = 0; ks < 2; ++ks) {
                #pragma unroll
                for (int nb = 0; nb < 4; ++nb) {
                    bf16x8 kf = *(const bf16x8*)(Ks + (nb * 16 + lrow) * 72 + ks * 32 + quad * 8);
                    sa[nb] = __builtin_amdgcn_mfma_f32_16x16x32_bf16(kf, qf[ks], sa[nb], 0, 0, 0);
                }
            }
            if (kt == qtile) {  // diagonal tile: causal mask
                int q = qbase + w * 16 + lrow;
                #pragma unroll
                for (int nb = 0; nb < 4; ++nb) {
                    int key = kt * 64 + nb * 16 + quad * 4;
                    #pragma unroll
                    for (int r = 0; r < 4; ++r)
                        if (key + r > q) sa[nb][r] = -3.0e4f;
                }
            }

            // online softmax (exp2 domain): in-lane over 16 keys + 2 shuffles
            float p[4][4];
            {
                float rm = sa[0][0];
                #pragma unroll
                for (int nb = 0; nb < 4; ++nb)
                    #pragma unroll
                    for (int r = 0; r < 4; ++r)
                        rm = fmaxf(rm, sa[nb][r]);
                rm = fmaxf(rm, __shfl_xor(rm, 16));
                rm = fmaxf(rm, __shfl_xor(rm, 32));
                float mnew = fmaxf(m_i, rm);
                float al = exp2f(m_i - mnew);
                m_i = mnew;
                float rs = 0.0f;
                #pragma unroll
                for (int nb = 0; nb < 4; ++nb)
                    #pragma unroll
                    for (int r = 0; r < 4; ++r) {
                        float e = exp2f(sa[nb][r] - mnew);
                        p[nb][r] = e;
                        rs += e;
                    }
                rs += __shfl_xor(rs, 16);
                rs += __shfl_xor(rs, 32);
                l_i = l_i * al + rs;
                #pragma unroll
                for (int nb = 0; nb < 4; ++nb)
                    #pragma unroll
                    for (int r = 0; r < 4; ++r)
                        o_acc[nb][r] *= al;
            }

            // P -> LDS [query][key], packed b64 (keys quad*4..quad*4+3)
            bf16* Pw = Ps + w * 16 * 72;
            #pragma unroll
            for (int nb = 0; nb < 4; ++nb) {
                bf16x4 pk;
                #pragma unroll
                for (int r = 0; r < 4; ++r)
                    pk[r] = (bf16)p[nb][r];
                *(bf16x4*)(Pw + lrow * 72 + nb * 16 + quad * 4) = pk;
            }
            asm volatile("s_waitcnt lgkmcnt(0)" ::: "memory");

            // O^T += V^T P^T: A=V^T[hd][key], B=P[query][key]
            #pragma unroll
            for (int ks = 0; ks < 2; ++ks) {
                bf16x8 pf = *(const bf16x8*)(Pw + lrow * 72 + ks * 32 + quad * 8);
                #pragma unroll
                for (int nb = 0; nb < 4; ++nb) {
                    bf16x8 vf = *(const bf16x8*)(Vs + (nb * 16 + lrow) * 72 + ks * 32 + quad * 8);
                    o_acc[nb] = __builtin_amdgcn_mfma_f32_16x16x32_bf16(vf, pf, o_acc[nb], 0, 0, 0);
                }
            }
        }

        // epilogue: O^T regs -> O[b,s,d]; lane: s=query fixed, 4 consecutive hd
        {
            float inv = 1.0f / l_i;
            int s = qbase + w * 16 + lrow;
            #pragma unroll
            for (int nb = 0; nb < 4; ++nb) {
                bf16x4 pk;
                #pragma unroll
                for (int r = 0; r < 4; ++r)
                    pk[r] = (bf16)(o_acc[nb][r] * inv);
                *(bf16x4*)(O + ((size_t)b * S_ + s) * D_ + h * 64 + nb * 16 + quad * 4) = pk;
            }
        }
        __syncthreads();   // protect LDS before next half re-stages
    }
}

// ---------------- pass 3: output projection GEMM (fp32 out) ----------------
__global__ __launch_bounds__(256) void proj_gemm(
    const bf16* __restrict__ A, const bf16* __restrict__ WpT,
    const float* __restrict__ bp, float* __restrict__ out)
{
    __shared__ bf16 As[128 * 32];
    __shared__ bf16 Bs[128 * 32];

    const int t = threadIdx.x;
    const int lid = t & 63, w = t >> 6;
    const int wm = w & 1, wn = w >> 1;
    const int lrow = lid & 15, quad = lid >> 4;
    const int m0 = blockIdx.y * 128, n0 = blockIdx.x * 128;

    const bf16* Ag = A   + (size_t)m0 * D_;
    const bf16* Bg = WpT + (size_t)n0 * D_;

    const int row0 = t >> 2, k80 = (t & 3) << 3;
    const int row1 = (t + 256) >> 2;

    f32x4 acc[4][4] = {};

    for (int k0 = 0; k0 < D_; k0 += 32) {
        __syncthreads();
        __builtin_amdgcn_global_load_lds(GLB(Ag + (size_t)row0 * D_ + k0 + k80),
                                         LDS(As + t * 8), 16, 0, 0);
        __builtin_amdgcn_global_load_lds(GLB(Bg + (size_t)row0 * D_ + k0 + k80),
                                         LDS(Bs + t * 8), 16, 0, 0);
        __builtin_amdgcn_global_load_lds(GLB(Ag + (size_t)row1 * D_ + k0 + k80),
                                         LDS(As + t * 8 + 2048), 16, 0, 0);
        __builtin_amdgcn_global_load_lds(GLB(Bg + (size_t)row1 * D_ + k0 + k80),
                                         LDS(Bs + t * 8 + 2048), 16, 0, 0);
        __syncthreads();
        bf16x8 a[4], b[4];
        #pragma unroll
        for (int mb = 0; mb < 4; ++mb)
            a[mb] = *(const bf16x8*)(As + (wm * 64 + mb * 16 + lrow) * 32 + quad * 8);
        #pragma unroll
        for (int nb = 0; nb < 4; ++nb)
            b[nb] = *(const bf16x8*)(Bs + (wn * 64 + nb * 16 + lrow) * 32 + quad * 8);
        #pragma unroll
        for (int mb = 0; mb < 4; ++mb)
            #pragma unroll
            for (int nb = 0; nb < 4; ++nb)
                acc[mb][nb] = __builtin_amdgcn_mfma_f32_16x16x32_bf16(a[mb], b[nb], acc[mb][nb], 0, 0, 0);
    }

    #pragma unroll
    for (int mb = 0; mb < 4; ++mb) {
        #pragma unroll
        for (int nb = 0; nb < 4; ++nb) {
            int gn = n0 + wn * 64 + nb * 16 + lrow;
            float bsv = bp[gn];
            #pragma unroll
            for (int r = 0; r < 4; ++r) {
                int gm = m0 + wm * 64 + mb * 16 + quad * 4 + r;
                out[(size_t)gm * D_ + gn] = acc[mb][nb][r] + bsv;
            }
        }
    }
}

// ---------------- launch ----------------
extern "C" void kernel_launch(void* const* d_in, const int* in_sizes, int n_in,
                              void* d_out, int out_size, void* d_ws, size_t ws_size,
                              hipStream_t stream)
{
    const float* x  = (const float*)d_in[0];
    const float* Wq = (const float*)d_in[1];
    const float* bq = (const float*)d_in[2];
    const float* Wk = (const float*)d_in[3];
    const float* bk = (const float*)d_in[4];
    const float* Wv = (const float*)d_in[5];
    const float* bv = (const float*)d_in[6];
    const float* Wp = (const float*)d_in[7];
    const float* bp = (const float*)d_in[8];

    bf16* ws = (bf16*)d_ws;
    const size_t WSZ = (size_t)D_ * D_;        // 1,048,576 elems
    const size_t BIG = (size_t)B_ * S_ * D_;   // 8,388,608 elems
    bf16* WqT = ws;
    bf16* WkT = WqT + WSZ;
    bf16* WvT = WkT + WSZ;
    bf16* WpT = WvT + WSZ;
    bf16* Qb  = WpT + WSZ;
    bf16* Kb  = Qb + BIG;
    bf16* Vb  = Kb + BIG;    // V^T layout [b,h,hd,s]
    bf16* Ab  = Vb + BIG;    // X(bf16) during qkv, then attention output

    transpose_cvt<<<dim3(32, 32, 4), 256, 0, stream>>>(
        Wq, Wk, Wv, Wp, WqT, WkT, WvT, WpT);

    cvt_x<<<dim3(4096), 256, 0, stream>>>(x, Ab);

    qkv_gemm<<<dim3(8, 64, 3), 256, 0, stream>>>(
        Ab, WqT, WkT, WvT, bq, bk, bv, Qb, Kb, Vb);

    attn_fwd<<<dim3(16, 64), 256, 0, stream>>>(Qb, Kb, Vb, Ab);

    proj_gemm<<<dim3(8, 64), 256, 0, stream>>>(Ab, WpT, bp, (float*)d_out);
}